// Round 1
// baseline (2613.209 us; speedup 1.0000x reference)
//
#include <hip/hip_runtime.h>

#define N_NODES 50000
#define N_EDGES 800000
#define N_GRAPHS 64

// ---------------- degree / normalization ----------------

__global__ void k_init_deg(float* deg, int n) {
    int i = blockIdx.x * blockDim.x + threadIdx.x;
    if (i < n) deg[i] = 1.0f;  // self-loop contributes 1
}

__global__ void k_deg_edges(const int* __restrict__ dst, float* deg, int E) {
    int i = blockIdx.x * blockDim.x + threadIdx.x;
    if (i < E) atomicAdd(&deg[dst[i]], 1.0f);
}

__global__ void k_rsqrt_inplace(float* deg, int n) {
    int i = blockIdx.x * blockDim.x + threadIdx.x;
    if (i < n) deg[i] = rsqrtf(deg[i]);  // deg >= 1 always (self loops)
}

// ---------------- dense GEMM: C[N,FOUT] = A[N,FIN] @ W[FIN,FOUT] ----------------

template <int FIN, int FOUT, int ROWS>
__global__ void k_gemm(const float* __restrict__ A, const float* __restrict__ W,
                       float* __restrict__ C, int N) {
    __shared__ float Ws[FIN * FOUT];
    const int T = ROWS * FOUT;  // blockDim.x
    for (int i = threadIdx.x; i < FIN * FOUT; i += T) Ws[i] = W[i];
    __syncthreads();
    int row = blockIdx.x * ROWS + threadIdx.x / FOUT;
    int col = threadIdx.x % FOUT;
    if (row >= N) return;
    const float* a = A + (size_t)row * FIN;
    float acc = 0.f;
#pragma unroll 8
    for (int k = 0; k < FIN; ++k) acc = fmaf(a[k], Ws[k * FOUT + col], acc);
    C[(size_t)row * FOUT + col] = acc;
}

// ---------------- GCN aggregation ----------------

// out[n,f] = h[n,f] * dinv[n]^2   (the self-loop term; also initializes out)
template <int F>
__global__ void k_selfloop(const float* __restrict__ h, const float* __restrict__ dinv,
                           float* __restrict__ out, int N) {
    int tid = blockIdx.x * blockDim.x + threadIdx.x;
    int n = tid / F;
    if (n >= N) return;
    float di = dinv[n];
    out[tid] = h[tid] * di * di;
}

// out[dst,f] += h[src,f] * dinv[src]*dinv[dst], float4 per thread
template <int F4>  // F/4
__global__ void k_scatter(const int* __restrict__ src, const int* __restrict__ dst,
                          const float* __restrict__ dinv, const float* __restrict__ h,
                          float* __restrict__ out, int E) {
    int tid = blockIdx.x * blockDim.x + threadIdx.x;
    int e = tid / F4, q = tid % F4;
    if (e >= E) return;
    int s = src[e], d = dst[e];
    float norm = dinv[s] * dinv[d];
    float4 v = ((const float4*)h)[(size_t)s * F4 + q];
    float* o = out + ((size_t)d * F4 + q) * 4;
    atomicAdd(o + 0, v.x * norm);
    atomicAdd(o + 1, v.y * norm);
    atomicAdd(o + 2, v.z * norm);
    atomicAdd(o + 3, v.w * norm);
}

template <int F>
__global__ void k_bias_relu(float* __restrict__ x, const float* __restrict__ b, int N) {
    int tid = blockIdx.x * blockDim.x + threadIdx.x;
    if (tid >= N * F) return;
    int f = tid % F;
    float v = x[tid] + b[f];
    x[tid] = v > 0.f ? v : 0.f;
}

// ---------------- global mean pool (batch is sorted) ----------------

__global__ void k_pool(const float* __restrict__ h, const int* __restrict__ batch,
                       float* __restrict__ sums, int N) {
    int n0 = blockIdx.x * 64;
    int f = threadIdx.x;  // 128 threads = one feature each
    int end = min(n0 + 64, N);
    int cur = batch[n0];
    float acc = 0.f;
    for (int n = n0; n < end; ++n) {
        int g = batch[n];
        float v = h[(size_t)n * 128 + f];
        if (g != cur) {
            atomicAdd(&sums[cur * 128 + f], acc);
            acc = 0.f;
            cur = g;
        }
        acc += v;
    }
    atomicAdd(&sums[cur * 128 + f], acc);
}

__global__ void k_counts(const int* __restrict__ batch, float* __restrict__ cnt, int N) {
    int i = blockIdx.x * blockDim.x + threadIdx.x;
    if (i < N) atomicAdd(&cnt[batch[i]], 1.0f);
}

// ---------------- MLP head: one block per graph ----------------

__global__ void k_mlp(const float* __restrict__ sums, const float* __restrict__ cnt,
                      const float* __restrict__ M1, const float* __restrict__ c1,
                      const float* __restrict__ M2, const float* __restrict__ c2,
                      const float* __restrict__ M3, const float* __restrict__ c3,
                      const float* __restrict__ M4, const float* __restrict__ c4,
                      float* __restrict__ out) {
    __shared__ float g[128], t1[64], t2[64], t3[64];
    int b = blockIdx.x;
    int t = threadIdx.x;
    if (t < 128) g[t] = sums[b * 128 + t] / fmaxf(cnt[b], 1.0f);
    __syncthreads();
    if (t < 64) {
        float acc = c1[t];
        for (int k = 0; k < 128; ++k) acc = fmaf(g[k], M1[k * 64 + t], acc);
        t1[t] = acc >= 0.f ? acc : 0.2f * acc;
    }
    __syncthreads();
    if (t < 64) {
        float acc = c2[t];
        for (int k = 0; k < 64; ++k) acc = fmaf(t1[k], M2[k * 64 + t], acc);
        t2[t] = acc >= 0.f ? acc : 0.1f * acc;
    }
    __syncthreads();
    if (t < 64) {
        float acc = c3[t];
        for (int k = 0; k < 64; ++k) acc = fmaf(t2[k], M3[k * 64 + t], acc);
        t3[t] = acc >= 0.f ? acc : 0.1f * acc;
    }
    __syncthreads();
    if (t == 0) {
        float acc = c4[0];
        for (int k = 0; k < 64; ++k) acc = fmaf(t3[k], M4[k], acc);
        out[b] = fmaxf(acc, 0.f);
    }
}

// ---------------- launch ----------------

extern "C" void kernel_launch(void* const* d_in, const int* in_sizes, int n_in,
                              void* d_out, int out_size, void* d_ws, size_t ws_size,
                              hipStream_t stream) {
    const float* x   = (const float*)d_in[0];
    const int*   ei  = (const int*)d_in[1];
    const int*   bat = (const int*)d_in[2];
    const float* W1  = (const float*)d_in[3];
    const float* b1  = (const float*)d_in[4];
    const float* W2  = (const float*)d_in[5];
    const float* b2  = (const float*)d_in[6];
    const float* M1  = (const float*)d_in[7];
    const float* c1  = (const float*)d_in[8];
    const float* M2  = (const float*)d_in[9];
    const float* c2  = (const float*)d_in[10];
    const float* M3  = (const float*)d_in[11];
    const float* c3  = (const float*)d_in[12];
    const float* M4  = (const float*)d_in[13];
    const float* c4  = (const float*)d_in[14];
    float* out = (float*)d_out;

    const int* src = ei;            // edge_index[0]
    const int* dst = ei + N_EDGES;  // edge_index[1]

    float* bufA = (float*)d_ws;                       // N*128 floats
    float* bufB = bufA + (size_t)N_NODES * 128;       // N*128 floats
    float* dinv = bufB + (size_t)N_NODES * 128;       // N floats
    float* sums = dinv + N_NODES;                     // 64*128
    float* cnt  = sums + N_GRAPHS * 128;              // 64

    // normalization coefficients
    k_init_deg<<<(N_NODES + 255) / 256, 256, 0, stream>>>(dinv, N_NODES);
    k_deg_edges<<<(N_EDGES + 255) / 256, 256, 0, stream>>>(dst, dinv, N_EDGES);
    k_rsqrt_inplace<<<(N_NODES + 255) / 256, 256, 0, stream>>>(dinv, N_NODES);

    // ---- conv1: x[50000,128] -> h1[50000,64] ----
    k_gemm<128, 64, 4><<<(N_NODES + 3) / 4, 256, 0, stream>>>(x, W1, bufA, N_NODES);
    k_selfloop<64><<<(N_NODES * 64 + 255) / 256, 256, 0, stream>>>(bufA, dinv, bufB, N_NODES);
    k_scatter<16><<<(N_EDGES * 16 + 255) / 256, 256, 0, stream>>>(src, dst, dinv, bufA, bufB, N_EDGES);
    k_bias_relu<64><<<(N_NODES * 64 + 255) / 256, 256, 0, stream>>>(bufB, b1, N_NODES);

    // ---- conv2: h1[50000,64] -> h2[50000,128] ----
    k_gemm<64, 128, 2><<<(N_NODES + 1) / 2, 256, 0, stream>>>(bufB, W2, bufA, N_NODES);
    k_selfloop<128><<<(N_NODES * 128 + 255) / 256, 256, 0, stream>>>(bufA, dinv, bufB, N_NODES);
    k_scatter<32><<<(N_EDGES * 32 + 255) / 256, 256, 0, stream>>>(src, dst, dinv, bufA, bufB, N_EDGES);
    k_bias_relu<128><<<(N_NODES * 128 + 255) / 256, 256, 0, stream>>>(bufB, b2, N_NODES);

    // ---- pool + MLP ----
    hipMemsetAsync(sums, 0, (N_GRAPHS * 128 + N_GRAPHS) * sizeof(float), stream);
    k_pool<<<(N_NODES + 63) / 64, 128, 0, stream>>>(bufB, bat, sums, N_NODES);
    k_counts<<<(N_NODES + 255) / 256, 256, 0, stream>>>(bat, cnt, N_NODES);
    k_mlp<<<N_GRAPHS, 128, 0, stream>>>(sums, cnt, M1, c1, M2, c2, M3, c3, M4, c4, out);
}

// Round 2
// 761.801 us; speedup vs baseline: 3.4303x; 3.4303x over previous
//
#include <hip/hip_runtime.h>

#define N_NODES 50000
#define N_EDGES 800000
#define N_GRAPHS 64

#define SCAN_BLOCK 256
#define SCAN_ITEMS 4
#define SCAN_CHUNK (SCAN_BLOCK * SCAN_ITEMS)                  // 1024
#define NB_SCAN ((N_NODES + SCAN_CHUNK - 1) / SCAN_CHUNK)     // 49

// ---------------- CSR build ----------------

__global__ void k_deg_edges(const int* __restrict__ dst, int* __restrict__ deg, int E) {
    int i = blockIdx.x * blockDim.x + threadIdx.x;
    if (i < E) atomicAdd(&deg[dst[i]], 1);
}

__global__ void k_scan1(const int* __restrict__ deg, int* __restrict__ part) {
    __shared__ int lds[SCAN_BLOCK];
    int b = blockIdx.x, t = threadIdx.x;
    int base = b * SCAN_CHUNK + t * SCAN_ITEMS;
    int s = 0;
#pragma unroll
    for (int k = 0; k < SCAN_ITEMS; ++k) {
        int i = base + k;
        if (i < N_NODES) s += deg[i];
    }
    lds[t] = s;
    __syncthreads();
    for (int off = SCAN_BLOCK / 2; off > 0; off >>= 1) {
        if (t < off) lds[t] += lds[t + off];
        __syncthreads();
    }
    if (t == 0) part[b] = lds[0];
}

__global__ void k_scan2(int* part, int* row_ptr) {
    int run = 0;
    for (int i = 0; i < NB_SCAN; ++i) { int v = part[i]; part[i] = run; run += v; }
    row_ptr[N_NODES] = run;
}

__global__ void k_scan3(const int* __restrict__ deg, const int* __restrict__ part,
                        int* __restrict__ row_ptr, int* __restrict__ fill,
                        float* __restrict__ dinv) {
    __shared__ int lds[SCAN_BLOCK];
    int b = blockIdx.x, t = threadIdx.x;
    int base = b * SCAN_CHUNK + t * SCAN_ITEMS;
    int v[SCAN_ITEMS];
    int s = 0;
#pragma unroll
    for (int k = 0; k < SCAN_ITEMS; ++k) {
        int i = base + k;
        v[k] = (i < N_NODES) ? deg[i] : 0;
        s += v[k];
    }
    lds[t] = s;
    __syncthreads();
    // Hillis-Steele inclusive scan over thread totals
    for (int off = 1; off < SCAN_BLOCK; off <<= 1) {
        int val = (t >= off) ? lds[t - off] : 0;
        __syncthreads();
        lds[t] += val;
        __syncthreads();
    }
    int excl = (t == 0 ? 0 : lds[t - 1]) + part[b];
#pragma unroll
    for (int k = 0; k < SCAN_ITEMS; ++k) {
        int i = base + k;
        if (i < N_NODES) {
            row_ptr[i] = excl;
            fill[i] = excl;
            dinv[i] = rsqrtf((float)(v[k] + 1));  // +1 self loop
            excl += v[k];
        }
    }
}

__global__ void k_fill(const int* __restrict__ src, const int* __restrict__ dst,
                       int* __restrict__ fill, int* __restrict__ csr, int E) {
    int e = blockIdx.x * blockDim.x + threadIdx.x;
    if (e < E) {
        int pos = atomicAdd(&fill[dst[e]], 1);
        csr[pos] = src[e];
    }
}

// ---------------- dense GEMM: C[N,FOUT] = A[N,FIN] @ W[FIN,FOUT] ----------------

template <int FIN, int FOUT, int ROWS>
__global__ void k_gemm(const float* __restrict__ A, const float* __restrict__ W,
                       float* __restrict__ C, int N) {
    __shared__ float Ws[FIN * FOUT];
    const int T = ROWS * FOUT;
    for (int i = threadIdx.x; i < FIN * FOUT; i += T) Ws[i] = W[i];
    __syncthreads();
    int row = blockIdx.x * ROWS + threadIdx.x / FOUT;
    int col = threadIdx.x % FOUT;
    if (row >= N) return;
    const float* a = A + (size_t)row * FIN;
    float acc = 0.f;
#pragma unroll 8
    for (int k = 0; k < FIN; ++k) acc = fmaf(a[k], Ws[k * FOUT + col], acc);
    C[(size_t)row * FOUT + col] = acc;
}

// ---------------- fused aggregate + bias + relu (gather, no atomics) ----------------
// out[n,f] = relu(b[f] + dinv[n] * (sum_s dinv[s]*h[s,f] + dinv[n]*h[n,f]))

__global__ void k_aggregate64(const float* __restrict__ h, const float* __restrict__ dinv,
                              const int* __restrict__ row_ptr, const int* __restrict__ csr,
                              const float* __restrict__ bias, float* __restrict__ out, int N) {
    int node = blockIdx.x * 4 + (threadIdx.x >> 6);  // one wave per node
    int f = threadIdx.x & 63;
    if (node >= N) return;
    float di = dinv[node];
    float acc = h[(size_t)node * 64 + f] * di;  // self loop (x di at end)
    int beg = row_ptr[node], end = row_ptr[node + 1];
    for (int j = beg; j < end; ++j) {
        int s = csr[j];
        acc = fmaf(dinv[s], h[(size_t)s * 64 + f], acc);
    }
    float v = fmaf(acc, di, bias[f]);
    out[(size_t)node * 64 + f] = v > 0.f ? v : 0.f;
}

__global__ void k_aggregate128(const float* __restrict__ h, const float* __restrict__ dinv,
                               const int* __restrict__ row_ptr, const int* __restrict__ csr,
                               const float* __restrict__ bias, float* __restrict__ out, int N) {
    int node = blockIdx.x * 4 + (threadIdx.x >> 6);  // one wave per node, 2 feats/lane
    int f2 = (threadIdx.x & 63);                     // float2 index
    if (node >= N) return;
    const float2* h2 = (const float2*)h;
    float di = dinv[node];
    float2 sv = h2[(size_t)node * 64 + f2];
    float accx = sv.x * di, accy = sv.y * di;
    int beg = row_ptr[node], end = row_ptr[node + 1];
    for (int j = beg; j < end; ++j) {
        int s = csr[j];
        float ds = dinv[s];
        float2 v = h2[(size_t)s * 64 + f2];
        accx = fmaf(ds, v.x, accx);
        accy = fmaf(ds, v.y, accy);
    }
    float bx = bias[f2 * 2], by = bias[f2 * 2 + 1];
    float ox = fmaf(accx, di, bx);
    float oy = fmaf(accy, di, by);
    float2 o;
    o.x = ox > 0.f ? ox : 0.f;
    o.y = oy > 0.f ? oy : 0.f;
    ((float2*)out)[(size_t)node * 64 + f2] = o;
}

// ---------------- global mean pool (batch is sorted) ----------------

__global__ void k_pool(const float* __restrict__ h, const int* __restrict__ batch,
                       float* __restrict__ sums, int N) {
    int n0 = blockIdx.x * 64;
    int f = threadIdx.x;  // 128 threads = one feature each
    int end = min(n0 + 64, N);
    int cur = batch[n0];
    float acc = 0.f;
    for (int n = n0; n < end; ++n) {
        int g = batch[n];
        float v = h[(size_t)n * 128 + f];
        if (g != cur) {
            atomicAdd(&sums[cur * 128 + f], acc);
            acc = 0.f;
            cur = g;
        }
        acc += v;
    }
    atomicAdd(&sums[cur * 128 + f], acc);
}

__global__ void k_counts(const int* __restrict__ batch, float* __restrict__ cnt, int N) {
    int i = blockIdx.x * blockDim.x + threadIdx.x;
    if (i < N) atomicAdd(&cnt[batch[i]], 1.0f);
}

// ---------------- MLP head: one block per graph ----------------

__global__ void k_mlp(const float* __restrict__ sums, const float* __restrict__ cnt,
                      const float* __restrict__ M1, const float* __restrict__ c1,
                      const float* __restrict__ M2, const float* __restrict__ c2,
                      const float* __restrict__ M3, const float* __restrict__ c3,
                      const float* __restrict__ M4, const float* __restrict__ c4,
                      float* __restrict__ out) {
    __shared__ float g[128], t1[64], t2[64], t3[64];
    int b = blockIdx.x;
    int t = threadIdx.x;
    if (t < 128) g[t] = sums[b * 128 + t] / fmaxf(cnt[b], 1.0f);
    __syncthreads();
    if (t < 64) {
        float acc = c1[t];
        for (int k = 0; k < 128; ++k) acc = fmaf(g[k], M1[k * 64 + t], acc);
        t1[t] = acc >= 0.f ? acc : 0.2f * acc;
    }
    __syncthreads();
    if (t < 64) {
        float acc = c2[t];
        for (int k = 0; k < 64; ++k) acc = fmaf(t1[k], M2[k * 64 + t], acc);
        t2[t] = acc >= 0.f ? acc : 0.1f * acc;
    }
    __syncthreads();
    if (t < 64) {
        float acc = c3[t];
        for (int k = 0; k < 64; ++k) acc = fmaf(t2[k], M3[k * 64 + t], acc);
        t3[t] = acc >= 0.f ? acc : 0.1f * acc;
    }
    __syncthreads();
    if (t == 0) {
        float acc = c4[0];
        for (int k = 0; k < 64; ++k) acc = fmaf(t3[k], M4[k], acc);
        out[b] = fmaxf(acc, 0.f);
    }
}

// ---------------- launch ----------------

extern "C" void kernel_launch(void* const* d_in, const int* in_sizes, int n_in,
                              void* d_out, int out_size, void* d_ws, size_t ws_size,
                              hipStream_t stream) {
    const float* x   = (const float*)d_in[0];
    const int*   ei  = (const int*)d_in[1];
    const int*   bat = (const int*)d_in[2];
    const float* W1  = (const float*)d_in[3];
    const float* b1  = (const float*)d_in[4];
    const float* W2  = (const float*)d_in[5];
    const float* b2  = (const float*)d_in[6];
    const float* M1  = (const float*)d_in[7];
    const float* c1  = (const float*)d_in[8];
    const float* M2  = (const float*)d_in[9];
    const float* c2  = (const float*)d_in[10];
    const float* M3  = (const float*)d_in[11];
    const float* c3  = (const float*)d_in[12];
    const float* M4  = (const float*)d_in[13];
    const float* c4  = (const float*)d_in[14];
    float* out = (float*)d_out;

    const int* src = ei;            // edge_index[0]
    const int* dst = ei + N_EDGES;  // edge_index[1]

    // workspace layout
    float* bufA    = (float*)d_ws;                          // N*128 f
    float* bufB    = bufA + (size_t)N_NODES * 128;          // N*128 f
    float* dinv    = bufB + (size_t)N_NODES * 128;          // N f
    float* sums    = dinv + N_NODES;                        // 64*128 f
    float* cnt     = sums + N_GRAPHS * 128;                 // 64 f
    int*   deg     = (int*)(cnt + N_GRAPHS);                // N i
    int*   row_ptr = deg + N_NODES;                         // N+1 i
    int*   fill    = row_ptr + N_NODES + 1;                 // N i
    int*   part    = fill + N_NODES;                        // 64 i
    int*   csr     = part + 64;                             // E i

    // ---- CSR build + normalization ----
    hipMemsetAsync(deg, 0, N_NODES * sizeof(int), stream);
    hipMemsetAsync(sums, 0, (N_GRAPHS * 128 + N_GRAPHS) * sizeof(float), stream);
    k_deg_edges<<<(N_EDGES + 255) / 256, 256, 0, stream>>>(dst, deg, N_EDGES);
    k_scan1<<<NB_SCAN, SCAN_BLOCK, 0, stream>>>(deg, part);
    k_scan2<<<1, 1, 0, stream>>>(part, row_ptr);
    k_scan3<<<NB_SCAN, SCAN_BLOCK, 0, stream>>>(deg, part, row_ptr, fill, dinv);
    k_fill<<<(N_EDGES + 255) / 256, 256, 0, stream>>>(src, dst, fill, csr, N_EDGES);

    // ---- conv1: x[50000,128] -> h1[50000,64] ----
    k_gemm<128, 64, 4><<<(N_NODES + 3) / 4, 256, 0, stream>>>(x, W1, bufA, N_NODES);
    k_aggregate64<<<(N_NODES + 3) / 4, 256, 0, stream>>>(bufA, dinv, row_ptr, csr, b1, bufB, N_NODES);

    // ---- conv2: h1[50000,64] -> h2[50000,128] ----
    k_gemm<64, 128, 2><<<(N_NODES + 1) / 2, 256, 0, stream>>>(bufB, W2, bufA, N_NODES);
    k_aggregate128<<<(N_NODES + 3) / 4, 256, 0, stream>>>(bufA, dinv, row_ptr, csr, b2, bufB, N_NODES);

    // ---- pool + MLP ----
    k_pool<<<(N_NODES + 63) / 64, 128, 0, stream>>>(bufB, bat, sums, N_NODES);
    k_counts<<<(N_NODES + 255) / 256, 256, 0, stream>>>(bat, cnt, N_NODES);
    k_mlp<<<N_GRAPHS, 128, 0, stream>>>(sums, cnt, M1, c1, M2, c2, M3, c3, M4, c4, out);
}

// Round 3
// 516.900 us; speedup vs baseline: 5.0555x; 1.4738x over previous
//
#include <hip/hip_runtime.h>

#define N_NODES 50000
#define N_EDGES 800000
#define N_GRAPHS 64

#define SCAN_BLOCK 256
#define SCAN_ITEMS 4
#define SCAN_CHUNK (SCAN_BLOCK * SCAN_ITEMS)                  // 1024
#define NB_SCAN ((N_NODES + SCAN_CHUNK - 1) / SCAN_CHUNK)     // 49

// ---------------- CSR build ----------------

__global__ void k_deg_edges(const int* __restrict__ dst, int* __restrict__ deg, int E) {
    int i = blockIdx.x * blockDim.x + threadIdx.x;
    if (i < E) atomicAdd(&deg[dst[i]], 1);
}

__global__ void k_scan1(const int* __restrict__ deg, int* __restrict__ part) {
    __shared__ int lds[SCAN_BLOCK];
    int b = blockIdx.x, t = threadIdx.x;
    int base = b * SCAN_CHUNK + t * SCAN_ITEMS;
    int s = 0;
#pragma unroll
    for (int k = 0; k < SCAN_ITEMS; ++k) {
        int i = base + k;
        if (i < N_NODES) s += deg[i];
    }
    lds[t] = s;
    __syncthreads();
    for (int off = SCAN_BLOCK / 2; off > 0; off >>= 1) {
        if (t < off) lds[t] += lds[t + off];
        __syncthreads();
    }
    if (t == 0) part[b] = lds[0];
}

__global__ void k_scan2(int* part, int* row_ptr) {
    int run = 0;
    for (int i = 0; i < NB_SCAN; ++i) { int v = part[i]; part[i] = run; run += v; }
    row_ptr[N_NODES] = run;
}

__global__ void k_scan3(const int* __restrict__ deg, const int* __restrict__ part,
                        int* __restrict__ row_ptr, int* __restrict__ fill,
                        float* __restrict__ dinv) {
    __shared__ int lds[SCAN_BLOCK];
    int b = blockIdx.x, t = threadIdx.x;
    int base = b * SCAN_CHUNK + t * SCAN_ITEMS;
    int v[SCAN_ITEMS];
    int s = 0;
#pragma unroll
    for (int k = 0; k < SCAN_ITEMS; ++k) {
        int i = base + k;
        v[k] = (i < N_NODES) ? deg[i] : 0;
        s += v[k];
    }
    lds[t] = s;
    __syncthreads();
    for (int off = 1; off < SCAN_BLOCK; off <<= 1) {
        int val = (t >= off) ? lds[t - off] : 0;
        __syncthreads();
        lds[t] += val;
        __syncthreads();
    }
    int excl = (t == 0 ? 0 : lds[t - 1]) + part[b];
#pragma unroll
    for (int k = 0; k < SCAN_ITEMS; ++k) {
        int i = base + k;
        if (i < N_NODES) {
            row_ptr[i] = excl;
            fill[i] = excl;
            dinv[i] = rsqrtf((float)(v[k] + 1));  // +1 self loop
            excl += v[k];
        }
    }
}

__global__ void k_fill(const int* __restrict__ src, const int* __restrict__ dst,
                       int* __restrict__ fill, int* __restrict__ csr, int E) {
    int e = blockIdx.x * blockDim.x + threadIdx.x;
    if (e < E) {
        int pos = atomicAdd(&fill[dst[e]], 1);
        csr[pos] = src[e];
    }
}

// ---------------- dense GEMM: C[N,FOUT] = A[N,FIN] @ W[FIN,FOUT] ----------------

template <int FIN, int FOUT, int ROWS>
__global__ void k_gemm(const float* __restrict__ A, const float* __restrict__ W,
                       float* __restrict__ C, int N) {
    __shared__ float Ws[FIN * FOUT];
    const int T = ROWS * FOUT;
    for (int i = threadIdx.x; i < FIN * FOUT; i += T) Ws[i] = W[i];
    __syncthreads();
    int row = blockIdx.x * ROWS + threadIdx.x / FOUT;
    int col = threadIdx.x % FOUT;
    if (row >= N) return;
    const float4* a4 = (const float4*)(A + (size_t)row * FIN);
    float acc = 0.f;
#pragma unroll
    for (int k4 = 0; k4 < FIN / 4; ++k4) {
        float4 a = a4[k4];
        int k = k4 * 4;
        acc = fmaf(a.x, Ws[(k + 0) * FOUT + col], acc);
        acc = fmaf(a.y, Ws[(k + 1) * FOUT + col], acc);
        acc = fmaf(a.z, Ws[(k + 2) * FOUT + col], acc);
        acc = fmaf(a.w, Ws[(k + 3) * FOUT + col], acc);
    }
    C[(size_t)row * FOUT + col] = acc;
}

// ---------------- fused aggregate + bias + relu (gather, no atomics) ----------------
// out[n,f] = relu(b[f] + dinv[n] * (sum_s dinv[s]*h[s,f] + dinv[n]*h[n,f]))

__global__ void k_aggregate64(const float* __restrict__ h, const float* __restrict__ dinv,
                              const int* __restrict__ row_ptr, const int* __restrict__ csr,
                              const float* __restrict__ bias, float* __restrict__ out, int N) {
    int node = blockIdx.x * 4 + (threadIdx.x >> 6);  // one wave per node
    int f = threadIdx.x & 63;
    if (node >= N) return;
    float di = dinv[node];
    float acc = h[(size_t)node * 64 + f] * di;  // self loop (x di at end)
    int beg = row_ptr[node], end = row_ptr[node + 1];
    for (int j = beg; j < end; ++j) {
        int s = csr[j];
        acc = fmaf(dinv[s], h[(size_t)s * 64 + f], acc);
    }
    float v = fmaf(acc, di, bias[f]);
    out[(size_t)node * 64 + f] = v > 0.f ? v : 0.f;
}

__global__ void k_aggregate128(const float* __restrict__ h, const float* __restrict__ dinv,
                               const int* __restrict__ row_ptr, const int* __restrict__ csr,
                               const float* __restrict__ bias, float* __restrict__ out, int N) {
    int node = blockIdx.x * 4 + (threadIdx.x >> 6);  // one wave per node, 2 feats/lane
    int f2 = (threadIdx.x & 63);                     // float2 index
    if (node >= N) return;
    const float2* h2 = (const float2*)h;
    float di = dinv[node];
    float2 sv = h2[(size_t)node * 64 + f2];
    float accx = sv.x * di, accy = sv.y * di;
    int beg = row_ptr[node], end = row_ptr[node + 1];
    for (int j = beg; j < end; ++j) {
        int s = csr[j];
        float ds = dinv[s];
        float2 v = h2[(size_t)s * 64 + f2];
        accx = fmaf(ds, v.x, accx);
        accy = fmaf(ds, v.y, accy);
    }
    float bx = bias[f2 * 2], by = bias[f2 * 2 + 1];
    float ox = fmaf(accx, di, bx);
    float oy = fmaf(accy, di, by);
    float2 o;
    o.x = ox > 0.f ? ox : 0.f;
    o.y = oy > 0.f ? oy : 0.f;
    ((float2*)out)[(size_t)node * 64 + f2] = o;
}

// ---------------- global mean pool + counts (batch is sorted) ----------------

__global__ void k_pool(const float* __restrict__ h, const int* __restrict__ batch,
                       float* __restrict__ sums, float* __restrict__ cnt, int N) {
    int n0 = blockIdx.x * 64;
    int f = threadIdx.x;  // 128 threads = one feature each
    int end = min(n0 + 64, N);
    int cur = batch[n0];
    float acc = 0.f, acc_c = 0.f;
    for (int n = n0; n < end; ++n) {
        int g = batch[n];
        float v = h[(size_t)n * 128 + f];
        if (g != cur) {
            atomicAdd(&sums[cur * 128 + f], acc);
            if (f == 0) atomicAdd(&cnt[cur], acc_c);
            acc = 0.f; acc_c = 0.f;
            cur = g;
        }
        acc += v;
        acc_c += 1.f;
    }
    atomicAdd(&sums[cur * 128 + f], acc);
    if (f == 0) atomicAdd(&cnt[cur], acc_c);
}

// ---------------- MLP head: one block per graph ----------------

__global__ void k_mlp(const float* __restrict__ sums, const float* __restrict__ cnt,
                      const float* __restrict__ M1, const float* __restrict__ c1,
                      const float* __restrict__ M2, const float* __restrict__ c2,
                      const float* __restrict__ M3, const float* __restrict__ c3,
                      const float* __restrict__ M4, const float* __restrict__ c4,
                      float* __restrict__ out) {
    __shared__ float g[128], t1[64], t2[64], t3[64];
    int b = blockIdx.x;
    int t = threadIdx.x;
    if (t < 128) g[t] = sums[b * 128 + t] / fmaxf(cnt[b], 1.0f);
    __syncthreads();
    if (t < 64) {
        float acc = c1[t];
        for (int k = 0; k < 128; ++k) acc = fmaf(g[k], M1[k * 64 + t], acc);
        t1[t] = acc >= 0.f ? acc : 0.2f * acc;
    }
    __syncthreads();
    if (t < 64) {
        float acc = c2[t];
        for (int k = 0; k < 64; ++k) acc = fmaf(t1[k], M2[k * 64 + t], acc);
        t2[t] = acc >= 0.f ? acc : 0.1f * acc;
    }
    __syncthreads();
    if (t < 64) {
        float acc = c3[t];
        for (int k = 0; k < 64; ++k) acc = fmaf(t2[k], M3[k * 64 + t], acc);
        t3[t] = acc >= 0.f ? acc : 0.1f * acc;
    }
    __syncthreads();
    if (t == 0) {
        float acc = c4[0];
        for (int k = 0; k < 64; ++k) acc = fmaf(t3[k], M4[k], acc);
        out[b] = fmaxf(acc, 0.f);
    }
}

// ---------------- launch ----------------

extern "C" void kernel_launch(void* const* d_in, const int* in_sizes, int n_in,
                              void* d_out, int out_size, void* d_ws, size_t ws_size,
                              hipStream_t stream) {
    const float* x   = (const float*)d_in[0];
    const int*   ei  = (const int*)d_in[1];
    const int*   bat = (const int*)d_in[2];
    const float* W1  = (const float*)d_in[3];
    const float* b1  = (const float*)d_in[4];
    const float* W2  = (const float*)d_in[5];
    const float* b2  = (const float*)d_in[6];
    const float* M1  = (const float*)d_in[7];
    const float* c1  = (const float*)d_in[8];
    const float* M2  = (const float*)d_in[9];
    const float* c2  = (const float*)d_in[10];
    const float* M3  = (const float*)d_in[11];
    const float* c3  = (const float*)d_in[12];
    const float* M4  = (const float*)d_in[13];
    const float* c4  = (const float*)d_in[14];
    float* out = (float*)d_out;

    const int* src = ei;            // edge_index[0]
    const int* dst = ei + N_EDGES;  // edge_index[1]

    // workspace layout
    float* bufA    = (float*)d_ws;                          // N*128 f
    float* bufB    = bufA + (size_t)N_NODES * 128;          // N*128 f
    float* dinv    = bufB + (size_t)N_NODES * 128;          // N f
    float* sums    = dinv + N_NODES;                        // 64*128 f
    float* cnt     = sums + N_GRAPHS * 128;                 // 64 f
    int*   deg     = (int*)(cnt + N_GRAPHS);                // N i
    int*   row_ptr = deg + N_NODES;                         // N+1 i
    int*   fill    = row_ptr + N_NODES + 1;                 // N i
    int*   part    = fill + N_NODES;                        // 64 i
    int*   csr     = part + 64;                             // E i

    // ---- CSR build + normalization ----
    hipMemsetAsync(deg, 0, N_NODES * sizeof(int), stream);
    hipMemsetAsync(sums, 0, (N_GRAPHS * 128 + N_GRAPHS) * sizeof(float), stream);
    k_deg_edges<<<(N_EDGES + 255) / 256, 256, 0, stream>>>(dst, deg, N_EDGES);
    k_scan1<<<NB_SCAN, SCAN_BLOCK, 0, stream>>>(deg, part);
    k_scan2<<<1, 1, 0, stream>>>(part, row_ptr);
    k_scan3<<<NB_SCAN, SCAN_BLOCK, 0, stream>>>(deg, part, row_ptr, fill, dinv);
    k_fill<<<(N_EDGES + 255) / 256, 256, 0, stream>>>(src, dst, fill, csr, N_EDGES);

    // ---- conv1: x[50000,128] -> h1[50000,64] ----
    k_gemm<128, 64, 4><<<(N_NODES + 3) / 4, 256, 0, stream>>>(x, W1, bufA, N_NODES);
    k_aggregate64<<<(N_NODES + 3) / 4, 256, 0, stream>>>(bufA, dinv, row_ptr, csr, b1, bufB, N_NODES);

    // ---- conv2: h1[50000,64] -> h2[50000,128] ----
    k_gemm<64, 128, 2><<<(N_NODES + 1) / 2, 256, 0, stream>>>(bufB, W2, bufA, N_NODES);
    k_aggregate128<<<(N_NODES + 3) / 4, 256, 0, stream>>>(bufA, dinv, row_ptr, csr, b2, bufB, N_NODES);

    // ---- pool + MLP ----
    k_pool<<<(N_NODES + 63) / 64, 128, 0, stream>>>(bufB, bat, sums, cnt, N_NODES);
    k_mlp<<<N_GRAPHS, 128, 0, stream>>>(sums, cnt, M1, c1, M2, c2, M3, c3, M4, c4, out);
}

// Round 4
// 424.943 us; speedup vs baseline: 6.1496x; 1.2164x over previous
//
#include <hip/hip_runtime.h>

#define N_NODES 50000
#define N_EDGES 800000
#define N_GRAPHS 64

#define SCAN_BLOCK 256
#define SCAN_ITEMS 4
#define SCAN_CHUNK (SCAN_BLOCK * SCAN_ITEMS)                  // 1024
#define NB_SCAN ((N_NODES + SCAN_CHUNK - 1) / SCAN_CHUNK)     // 49

// ---------------- CSR build ----------------

__global__ void k_deg_edges(const int* __restrict__ dst, int* __restrict__ deg, int E) {
    int i = blockIdx.x * blockDim.x + threadIdx.x;
    if (i < E) atomicAdd(&deg[dst[i]], 1);
}

__global__ void k_scan1(const int* __restrict__ deg, int* __restrict__ part) {
    __shared__ int lds[SCAN_BLOCK];
    int b = blockIdx.x, t = threadIdx.x;
    int base = b * SCAN_CHUNK + t * SCAN_ITEMS;
    int s = 0;
#pragma unroll
    for (int k = 0; k < SCAN_ITEMS; ++k) {
        int i = base + k;
        if (i < N_NODES) s += deg[i];
    }
    lds[t] = s;
    __syncthreads();
    for (int off = SCAN_BLOCK / 2; off > 0; off >>= 1) {
        if (t < off) lds[t] += lds[t + off];
        __syncthreads();
    }
    if (t == 0) part[b] = lds[0];
}

__global__ void k_scan2(int* part, int* row_ptr) {
    int run = 0;
    for (int i = 0; i < NB_SCAN; ++i) { int v = part[i]; part[i] = run; run += v; }
    row_ptr[N_NODES] = run;
}

__global__ void k_scan3(const int* __restrict__ deg, const int* __restrict__ part,
                        int* __restrict__ row_ptr, int* __restrict__ fill,
                        float* __restrict__ dinv) {
    __shared__ int lds[SCAN_BLOCK];
    int b = blockIdx.x, t = threadIdx.x;
    int base = b * SCAN_CHUNK + t * SCAN_ITEMS;
    int v[SCAN_ITEMS];
    int s = 0;
#pragma unroll
    for (int k = 0; k < SCAN_ITEMS; ++k) {
        int i = base + k;
        v[k] = (i < N_NODES) ? deg[i] : 0;
        s += v[k];
    }
    lds[t] = s;
    __syncthreads();
    for (int off = 1; off < SCAN_BLOCK; off <<= 1) {
        int val = (t >= off) ? lds[t - off] : 0;
        __syncthreads();
        lds[t] += val;
        __syncthreads();
    }
    int excl = (t == 0 ? 0 : lds[t - 1]) + part[b];
#pragma unroll
    for (int k = 0; k < SCAN_ITEMS; ++k) {
        int i = base + k;
        if (i < N_NODES) {
            row_ptr[i] = excl;
            fill[i] = excl;
            dinv[i] = rsqrtf((float)(v[k] + 1));  // +1 self loop
            excl += v[k];
        }
    }
}

// csr entry = {src, bits(dinv[src])} — removes the dependent dinv gather in aggregates
__global__ void k_fill(const int* __restrict__ src, const int* __restrict__ dst,
                       const float* __restrict__ dinv,
                       int* __restrict__ fill, int2* __restrict__ csr, int E) {
    int e = blockIdx.x * blockDim.x + threadIdx.x;
    if (e < E) {
        int s = src[e];
        int pos = atomicAdd(&fill[dst[e]], 1);
        csr[pos] = make_int2(s, __float_as_int(dinv[s]));
    }
}

// ---------------- dense GEMM: C[N,FOUT] = A[N,FIN] @ W[FIN,FOUT] ----------------
// RELU_BIAS: C = relu(A@W + b) fused epilogue

template <int FIN, int FOUT, int ROWS, bool RELU_BIAS>
__global__ void k_gemm(const float* __restrict__ A, const float* __restrict__ W,
                       const float* __restrict__ bias, float* __restrict__ C, int N) {
    __shared__ float Ws[FIN * FOUT];
    const int T = ROWS * FOUT;
    for (int i = threadIdx.x; i < FIN * FOUT; i += T) Ws[i] = W[i];
    __syncthreads();
    int row = blockIdx.x * ROWS + threadIdx.x / FOUT;
    int col = threadIdx.x % FOUT;
    if (row >= N) return;
    const float4* a4 = (const float4*)(A + (size_t)row * FIN);
    float acc = 0.f;
#pragma unroll
    for (int k4 = 0; k4 < FIN / 4; ++k4) {
        float4 a = a4[k4];
        int k = k4 * 4;
        acc = fmaf(a.x, Ws[(k + 0) * FOUT + col], acc);
        acc = fmaf(a.y, Ws[(k + 1) * FOUT + col], acc);
        acc = fmaf(a.z, Ws[(k + 2) * FOUT + col], acc);
        acc = fmaf(a.w, Ws[(k + 3) * FOUT + col], acc);
    }
    if (RELU_BIAS) {
        float v = acc + bias[col];
        C[(size_t)row * FOUT + col] = v > 0.f ? v : 0.f;
    } else {
        C[(size_t)row * FOUT + col] = acc;
    }
}

// ---------------- 64-wide aggregate (gather, no atomics) ----------------
// RELU: out = relu(bias + dinv[n]*(sum + dinv[n]*h[n]))   [conv1 epilogue]
// else: out = dinv[n]*(sum + dinv[n]*h[n])                [pre-GEMM for conv2]

template <bool RELU>
__global__ void k_agg64(const float* __restrict__ h, const float* __restrict__ dinv,
                        const int* __restrict__ row_ptr, const int2* __restrict__ csr,
                        const float* __restrict__ bias, float* __restrict__ out, int N) {
    int node = blockIdx.x * 4 + (threadIdx.x >> 6);  // one wave per node
    int f = threadIdx.x & 63;
    if (node >= N) return;
    float di = dinv[node];
    float acc0 = h[(size_t)node * 64 + f] * di;  // self loop
    float acc1 = 0.f, acc2 = 0.f, acc3 = 0.f;
    int beg = row_ptr[node], end = row_ptr[node + 1];
    int j = beg;
    for (; j + 4 <= end; j += 4) {
        int2 e0 = csr[j], e1 = csr[j + 1], e2 = csr[j + 2], e3 = csr[j + 3];
        float v0 = h[(size_t)e0.x * 64 + f];
        float v1 = h[(size_t)e1.x * 64 + f];
        float v2 = h[(size_t)e2.x * 64 + f];
        float v3 = h[(size_t)e3.x * 64 + f];
        acc0 = fmaf(__int_as_float(e0.y), v0, acc0);
        acc1 = fmaf(__int_as_float(e1.y), v1, acc1);
        acc2 = fmaf(__int_as_float(e2.y), v2, acc2);
        acc3 = fmaf(__int_as_float(e3.y), v3, acc3);
    }
    for (; j < end; ++j) {
        int2 e = csr[j];
        acc0 = fmaf(__int_as_float(e.y), h[(size_t)e.x * 64 + f], acc0);
    }
    float acc = (acc0 + acc1) + (acc2 + acc3);
    if (RELU) {
        float v = fmaf(acc, di, bias[f]);
        out[(size_t)node * 64 + f] = v > 0.f ? v : 0.f;
    } else {
        out[(size_t)node * 64 + f] = acc * di;
    }
}

// ---------------- global mean pool + counts (batch is sorted) ----------------

__global__ void k_pool(const float* __restrict__ h, const int* __restrict__ batch,
                       float* __restrict__ sums, float* __restrict__ cnt, int N) {
    int n0 = blockIdx.x * 64;
    int f = threadIdx.x;  // 128 threads = one feature each
    int end = min(n0 + 64, N);
    int cur = batch[n0];
    float acc = 0.f, acc_c = 0.f;
    for (int n = n0; n < end; ++n) {
        int g = batch[n];
        float v = h[(size_t)n * 128 + f];
        if (g != cur) {
            atomicAdd(&sums[cur * 128 + f], acc);
            if (f == 0) atomicAdd(&cnt[cur], acc_c);
            acc = 0.f; acc_c = 0.f;
            cur = g;
        }
        acc += v;
        acc_c += 1.f;
    }
    atomicAdd(&sums[cur * 128 + f], acc);
    if (f == 0) atomicAdd(&cnt[cur], acc_c);
}

// ---------------- MLP head: one block per graph ----------------

__global__ void k_mlp(const float* __restrict__ sums, const float* __restrict__ cnt,
                      const float* __restrict__ M1, const float* __restrict__ c1,
                      const float* __restrict__ M2, const float* __restrict__ c2,
                      const float* __restrict__ M3, const float* __restrict__ c3,
                      const float* __restrict__ M4, const float* __restrict__ c4,
                      float* __restrict__ out) {
    __shared__ float g[128], t1[64], t2[64], t3[64];
    int b = blockIdx.x;
    int t = threadIdx.x;
    if (t < 128) g[t] = sums[b * 128 + t] / fmaxf(cnt[b], 1.0f);
    __syncthreads();
    if (t < 64) {
        float acc = c1[t];
        for (int k = 0; k < 128; ++k) acc = fmaf(g[k], M1[k * 64 + t], acc);
        t1[t] = acc >= 0.f ? acc : 0.2f * acc;
    }
    __syncthreads();
    if (t < 64) {
        float acc = c2[t];
        for (int k = 0; k < 64; ++k) acc = fmaf(t1[k], M2[k * 64 + t], acc);
        t2[t] = acc >= 0.f ? acc : 0.1f * acc;
    }
    __syncthreads();
    if (t < 64) {
        float acc = c3[t];
        for (int k = 0; k < 64; ++k) acc = fmaf(t2[k], M3[k * 64 + t], acc);
        t3[t] = acc >= 0.f ? acc : 0.1f * acc;
    }
    __syncthreads();
    if (t == 0) {
        float acc = c4[0];
        for (int k = 0; k < 64; ++k) acc = fmaf(t3[k], M4[k], acc);
        out[b] = fmaxf(acc, 0.f);
    }
}

// ---------------- launch ----------------

extern "C" void kernel_launch(void* const* d_in, const int* in_sizes, int n_in,
                              void* d_out, int out_size, void* d_ws, size_t ws_size,
                              hipStream_t stream) {
    const float* x   = (const float*)d_in[0];
    const int*   ei  = (const int*)d_in[1];
    const int*   bat = (const int*)d_in[2];
    const float* W1  = (const float*)d_in[3];
    const float* b1  = (const float*)d_in[4];
    const float* W2  = (const float*)d_in[5];
    const float* b2  = (const float*)d_in[6];
    const float* M1  = (const float*)d_in[7];
    const float* c1  = (const float*)d_in[8];
    const float* M2  = (const float*)d_in[9];
    const float* c2  = (const float*)d_in[10];
    const float* M3  = (const float*)d_in[11];
    const float* c3  = (const float*)d_in[12];
    const float* M4  = (const float*)d_in[13];
    const float* c4  = (const float*)d_in[14];
    float* out = (float*)d_out;

    const int* src = ei;            // edge_index[0]
    const int* dst = ei + N_EDGES;  // edge_index[1]

    // workspace layout
    float* bufA    = (float*)d_ws;                          // N*128 f
    float* bufB    = bufA + (size_t)N_NODES * 128;          // N*128 f
    float* dinv    = bufB + (size_t)N_NODES * 128;          // N f
    float* sums    = dinv + N_NODES;                        // 64*128 f
    float* cnt     = sums + N_GRAPHS * 128;                 // 64 f
    int*   deg     = (int*)(cnt + N_GRAPHS);                // N i
    int*   row_ptr = deg + N_NODES;                         // N+1 i
    int*   fill    = row_ptr + N_NODES + 1;                 // N i
    int*   part    = fill + N_NODES;                        // 64 i (+ pad to even)
    int2*  csr     = (int2*)(part + 64);                    // E int2

    // ---- CSR build + normalization ----
    hipMemsetAsync(deg, 0, N_NODES * sizeof(int), stream);
    hipMemsetAsync(sums, 0, (N_GRAPHS * 128 + N_GRAPHS) * sizeof(float), stream);
    k_deg_edges<<<(N_EDGES + 255) / 256, 256, 0, stream>>>(dst, deg, N_EDGES);
    k_scan1<<<NB_SCAN, SCAN_BLOCK, 0, stream>>>(deg, part);
    k_scan2<<<1, 1, 0, stream>>>(part, row_ptr);
    k_scan3<<<NB_SCAN, SCAN_BLOCK, 0, stream>>>(deg, part, row_ptr, fill, dinv);
    k_fill<<<(N_EDGES + 255) / 256, 256, 0, stream>>>(src, dst, dinv, fill, csr, N_EDGES);

    // ---- conv1: h1 = relu(Â (x@W1) + b1), aggregate in 64-d ----
    k_gemm<128, 64, 4, false><<<(N_NODES + 3) / 4, 256, 0, stream>>>(x, W1, nullptr, bufA, N_NODES);
    k_agg64<true><<<(N_NODES + 3) / 4, 256, 0, stream>>>(bufA, dinv, row_ptr, csr, b1, bufB, N_NODES);

    // ---- conv2: h2 = relu((Â h1)@W2 + b2) — aggregate FIRST (64-d), then GEMM ----
    k_agg64<false><<<(N_NODES + 3) / 4, 256, 0, stream>>>(bufB, dinv, row_ptr, csr, nullptr, bufA, N_NODES);
    k_gemm<64, 128, 2, true><<<(N_NODES + 1) / 2, 256, 0, stream>>>(bufA, W2, b2, bufB, N_NODES);

    // ---- pool + MLP ----
    k_pool<<<(N_NODES + 63) / 64, 128, 0, stream>>>(bufB, bat, sums, cnt, N_NODES);
    k_mlp<<<N_GRAPHS, 128, 0, stream>>>(sums, cnt, M1, c1, M2, c2, M3, c3, M4, c4, out);
}

// Round 5
// 329.630 us; speedup vs baseline: 7.9277x; 1.2892x over previous
//
#include <hip/hip_runtime.h>

#define N_NODES 50000
#define N_EDGES 800000
#define N_GRAPHS 64

#define SCAN_BLOCK 256
#define SCAN_ITEMS 4
#define SCAN_CHUNK (SCAN_BLOCK * SCAN_ITEMS)                  // 1024
#define NB_SCAN ((N_NODES + SCAN_CHUNK - 1) / SCAN_CHUNK)     // 49

// ---------------- CSR build ----------------

__global__ void k_deg_edges(const int* __restrict__ dst, int* __restrict__ deg, int E) {
    int i = blockIdx.x * blockDim.x + threadIdx.x;
    if (i < E) atomicAdd(&deg[dst[i]], 1);
}

__global__ void k_scan1(const int* __restrict__ deg, int* __restrict__ part) {
    __shared__ int lds[SCAN_BLOCK];
    int b = blockIdx.x, t = threadIdx.x;
    int base = b * SCAN_CHUNK + t * SCAN_ITEMS;
    int s = 0;
#pragma unroll
    for (int k = 0; k < SCAN_ITEMS; ++k) {
        int i = base + k;
        if (i < N_NODES) s += deg[i];
    }
    lds[t] = s;
    __syncthreads();
    for (int off = SCAN_BLOCK / 2; off > 0; off >>= 1) {
        if (t < off) lds[t] += lds[t + off];
        __syncthreads();
    }
    if (t == 0) part[b] = lds[0];
}

__global__ void k_scan2(int* part, int* row_ptr) {
    int run = 0;
    for (int i = 0; i < NB_SCAN; ++i) { int v = part[i]; part[i] = run; run += v; }
    row_ptr[N_NODES] = run;
}

__global__ void k_scan3(const int* __restrict__ deg, const int* __restrict__ part,
                        int* __restrict__ row_ptr, int* __restrict__ fill,
                        float* __restrict__ dinv) {
    __shared__ int lds[SCAN_BLOCK];
    int b = blockIdx.x, t = threadIdx.x;
    int base = b * SCAN_CHUNK + t * SCAN_ITEMS;
    int v[SCAN_ITEMS];
    int s = 0;
#pragma unroll
    for (int k = 0; k < SCAN_ITEMS; ++k) {
        int i = base + k;
        v[k] = (i < N_NODES) ? deg[i] : 0;
        s += v[k];
    }
    lds[t] = s;
    __syncthreads();
    for (int off = 1; off < SCAN_BLOCK; off <<= 1) {
        int val = (t >= off) ? lds[t - off] : 0;
        __syncthreads();
        lds[t] += val;
        __syncthreads();
    }
    int excl = (t == 0 ? 0 : lds[t - 1]) + part[b];
#pragma unroll
    for (int k = 0; k < SCAN_ITEMS; ++k) {
        int i = base + k;
        if (i < N_NODES) {
            row_ptr[i] = excl;
            fill[i] = excl;
            dinv[i] = rsqrtf((float)(v[k] + 1));  // +1 self loop
            excl += v[k];
        }
    }
}

// csr entry = {src, bits(dinv[src])} — removes the dependent dinv gather in aggregates
__global__ void k_fill(const int* __restrict__ src, const int* __restrict__ dst,
                       const float* __restrict__ dinv,
                       int* __restrict__ fill, int2* __restrict__ csr, int E) {
    int e = blockIdx.x * blockDim.x + threadIdx.x;
    if (e < E) {
        int s = src[e];
        int pos = atomicAdd(&fill[dst[e]], 1);
        csr[pos] = make_int2(s, __float_as_int(dinv[s]));
    }
}

// ---------------- register-blocked GEMM ----------------
// C[N,WS](col slice coff..coff+63) = A[N,FIN] @ W[FIN,WS](cols coff..coff+63)
// 64 rows x 64 cols per block, 256 threads, 4x4 micro-tile per thread.

template <int FIN, int WS, bool RELU>
__global__ __launch_bounds__(256) void k_gemm_tile(const float* __restrict__ A,
                                                   const float* __restrict__ W,
                                                   const float* __restrict__ bias,
                                                   float* __restrict__ C, int N) {
    __shared__ __align__(16) float As[64 * (FIN + 2)];
    __shared__ __align__(16) float Wsm[FIN * 64];
    const int t = threadIdx.x;
    const int row0 = blockIdx.x * 64;
    const int coff = blockIdx.y * 64;

    // stage A tile (64 x FIN), float4 global loads, float2 LDS stores (row pad +2)
    const int NF4 = 64 * FIN / 4;
    for (int idx = t; idx < NF4; idx += 256) {
        int r = idx / (FIN / 4);
        int c4 = idx % (FIN / 4);
        float4 v = make_float4(0.f, 0.f, 0.f, 0.f);
        if (row0 + r < N) v = ((const float4*)(A + (size_t)(row0 + r) * FIN))[c4];
        float* p = &As[r * (FIN + 2) + c4 * 4];
        ((float2*)p)[0] = make_float2(v.x, v.y);
        ((float2*)p)[1] = make_float2(v.z, v.w);
    }
    // stage W column slice (FIN x 64)
    for (int idx = t; idx < FIN * 16; idx += 256) {
        int r = idx / 16, c4 = idx % 16;
        float4 v = ((const float4*)(W + (size_t)r * WS + coff))[c4];
        *((float4*)&Wsm[r * 64 + c4 * 4]) = v;
    }
    __syncthreads();

    const int tc = (t & 15) * 4;   // col group
    const int tr = (t >> 4) * 4;   // row group
    float acc[4][4] = {};
#pragma unroll 4
    for (int k = 0; k < FIN; k += 2) {
        float2 a[4];
#pragma unroll
        for (int r = 0; r < 4; ++r)
            a[r] = *(const float2*)&As[(tr + r) * (FIN + 2) + k];
        float4 w0 = *(const float4*)&Wsm[k * 64 + tc];
        float4 w1 = *(const float4*)&Wsm[(k + 1) * 64 + tc];
#pragma unroll
        for (int r = 0; r < 4; ++r) {
            acc[r][0] = fmaf(a[r].x, w0.x, acc[r][0]);
            acc[r][1] = fmaf(a[r].x, w0.y, acc[r][1]);
            acc[r][2] = fmaf(a[r].x, w0.z, acc[r][2]);
            acc[r][3] = fmaf(a[r].x, w0.w, acc[r][3]);
            acc[r][0] = fmaf(a[r].y, w1.x, acc[r][0]);
            acc[r][1] = fmaf(a[r].y, w1.y, acc[r][1]);
            acc[r][2] = fmaf(a[r].y, w1.z, acc[r][2]);
            acc[r][3] = fmaf(a[r].y, w1.w, acc[r][3]);
        }
    }

    float4 bv = make_float4(0.f, 0.f, 0.f, 0.f);
    if (RELU) bv = *(const float4*)&bias[coff + tc];
#pragma unroll
    for (int r = 0; r < 4; ++r) {
        int row = row0 + tr + r;
        if (row < N) {
            float4 v = make_float4(acc[r][0], acc[r][1], acc[r][2], acc[r][3]);
            if (RELU) {
                v.x = fmaxf(v.x + bv.x, 0.f);
                v.y = fmaxf(v.y + bv.y, 0.f);
                v.z = fmaxf(v.z + bv.z, 0.f);
                v.w = fmaxf(v.w + bv.w, 0.f);
            }
            *((float4*)(C + (size_t)row * WS + coff + tc)) = v;
        }
    }
}

// ---------------- 64-wide aggregate (gather, no atomics) ----------------
// RELU: out = relu(bias + dinv[n]*(sum + dinv[n]*h[n]))   [conv1 epilogue]
// else: out = dinv[n]*(sum + dinv[n]*h[n])                [pre-GEMM for conv2]

template <bool RELU>
__global__ void k_agg64(const float* __restrict__ h, const float* __restrict__ dinv,
                        const int* __restrict__ row_ptr, const int2* __restrict__ csr,
                        const float* __restrict__ bias, float* __restrict__ out, int N) {
    int node = blockIdx.x * 4 + (threadIdx.x >> 6);  // one wave per node
    int f = threadIdx.x & 63;
    if (node >= N) return;
    float di = dinv[node];
    float acc0 = h[(size_t)node * 64 + f] * di;  // self loop
    float acc1 = 0.f, acc2 = 0.f, acc3 = 0.f;
    int beg = row_ptr[node], end = row_ptr[node + 1];
    int j = beg;
    for (; j + 4 <= end; j += 4) {
        int2 e0 = csr[j], e1 = csr[j + 1], e2 = csr[j + 2], e3 = csr[j + 3];
        float v0 = h[(size_t)e0.x * 64 + f];
        float v1 = h[(size_t)e1.x * 64 + f];
        float v2 = h[(size_t)e2.x * 64 + f];
        float v3 = h[(size_t)e3.x * 64 + f];
        acc0 = fmaf(__int_as_float(e0.y), v0, acc0);
        acc1 = fmaf(__int_as_float(e1.y), v1, acc1);
        acc2 = fmaf(__int_as_float(e2.y), v2, acc2);
        acc3 = fmaf(__int_as_float(e3.y), v3, acc3);
    }
    for (; j < end; ++j) {
        int2 e = csr[j];
        acc0 = fmaf(__int_as_float(e.y), h[(size_t)e.x * 64 + f], acc0);
    }
    float acc = (acc0 + acc1) + (acc2 + acc3);
    if (RELU) {
        float v = fmaf(acc, di, bias[f]);
        out[(size_t)node * 64 + f] = v > 0.f ? v : 0.f;
    } else {
        out[(size_t)node * 64 + f] = acc * di;
    }
}

// ---------------- global mean pool + counts (batch is sorted) ----------------

__global__ void k_pool(const float* __restrict__ h, const int* __restrict__ batch,
                       float* __restrict__ sums, float* __restrict__ cnt, int N) {
    int n0 = blockIdx.x * 64;
    int f = threadIdx.x;  // 128 threads = one feature each
    int end = min(n0 + 64, N);
    int cur = batch[n0];
    float acc = 0.f, acc_c = 0.f;
    for (int n = n0; n < end; ++n) {
        int g = batch[n];
        float v = h[(size_t)n * 128 + f];
        if (g != cur) {
            atomicAdd(&sums[cur * 128 + f], acc);
            if (f == 0) atomicAdd(&cnt[cur], acc_c);
            acc = 0.f; acc_c = 0.f;
            cur = g;
        }
        acc += v;
        acc_c += 1.f;
    }
    atomicAdd(&sums[cur * 128 + f], acc);
    if (f == 0) atomicAdd(&cnt[cur], acc_c);
}

// ---------------- MLP head: one block per graph ----------------

__global__ void k_mlp(const float* __restrict__ sums, const float* __restrict__ cnt,
                      const float* __restrict__ M1, const float* __restrict__ c1,
                      const float* __restrict__ M2, const float* __restrict__ c2,
                      const float* __restrict__ M3, const float* __restrict__ c3,
                      const float* __restrict__ M4, const float* __restrict__ c4,
                      float* __restrict__ out) {
    __shared__ float g[128], t1[64], t2[64], t3[64];
    int b = blockIdx.x;
    int t = threadIdx.x;
    if (t < 128) g[t] = sums[b * 128 + t] / fmaxf(cnt[b], 1.0f);
    __syncthreads();
    if (t < 64) {
        float acc = c1[t];
        for (int k = 0; k < 128; ++k) acc = fmaf(g[k], M1[k * 64 + t], acc);
        t1[t] = acc >= 0.f ? acc : 0.2f * acc;
    }
    __syncthreads();
    if (t < 64) {
        float acc = c2[t];
        for (int k = 0; k < 64; ++k) acc = fmaf(t1[k], M2[k * 64 + t], acc);
        t2[t] = acc >= 0.f ? acc : 0.1f * acc;
    }
    __syncthreads();
    if (t < 64) {
        float acc = c3[t];
        for (int k = 0; k < 64; ++k) acc = fmaf(t2[k], M3[k * 64 + t], acc);
        t3[t] = acc >= 0.f ? acc : 0.1f * acc;
    }
    __syncthreads();
    if (t == 0) {
        float acc = c4[0];
        for (int k = 0; k < 64; ++k) acc = fmaf(t3[k], M4[k], acc);
        out[b] = fmaxf(acc, 0.f);
    }
}

// ---------------- launch ----------------

extern "C" void kernel_launch(void* const* d_in, const int* in_sizes, int n_in,
                              void* d_out, int out_size, void* d_ws, size_t ws_size,
                              hipStream_t stream) {
    const float* x   = (const float*)d_in[0];
    const int*   ei  = (const int*)d_in[1];
    const int*   bat = (const int*)d_in[2];
    const float* W1  = (const float*)d_in[3];
    const float* b1  = (const float*)d_in[4];
    const float* W2  = (const float*)d_in[5];
    const float* b2  = (const float*)d_in[6];
    const float* M1  = (const float*)d_in[7];
    const float* c1  = (const float*)d_in[8];
    const float* M2  = (const float*)d_in[9];
    const float* c2  = (const float*)d_in[10];
    const float* M3  = (const float*)d_in[11];
    const float* c3  = (const float*)d_in[12];
    const float* M4  = (const float*)d_in[13];
    const float* c4  = (const float*)d_in[14];
    float* out = (float*)d_out;

    const int* src = ei;            // edge_index[0]
    const int* dst = ei + N_EDGES;  // edge_index[1]

    // workspace layout
    float* bufA    = (float*)d_ws;                          // N*128 f
    float* bufB    = bufA + (size_t)N_NODES * 128;          // N*128 f
    float* dinv    = bufB + (size_t)N_NODES * 128;          // N f
    float* sums    = dinv + N_NODES;                        // 64*128 f
    float* cnt     = sums + N_GRAPHS * 128;                 // 64 f
    int*   deg     = (int*)(cnt + N_GRAPHS);                // N i
    int*   row_ptr = deg + N_NODES;                         // N+1 i
    int*   fill    = row_ptr + N_NODES + 1;                 // N i
    int*   part    = fill + N_NODES;                        // 64 i
    int2*  csr     = (int2*)(part + 64);                    // E int2

    // ---- CSR build + normalization ----
    hipMemsetAsync(deg, 0, N_NODES * sizeof(int), stream);
    hipMemsetAsync(sums, 0, (N_GRAPHS * 128 + N_GRAPHS) * sizeof(float), stream);
    k_deg_edges<<<(N_EDGES + 255) / 256, 256, 0, stream>>>(dst, deg, N_EDGES);
    k_scan1<<<NB_SCAN, SCAN_BLOCK, 0, stream>>>(deg, part);
    k_scan2<<<1, 1, 0, stream>>>(part, row_ptr);
    k_scan3<<<NB_SCAN, SCAN_BLOCK, 0, stream>>>(deg, part, row_ptr, fill, dinv);
    k_fill<<<(N_EDGES + 255) / 256, 256, 0, stream>>>(src, dst, dinv, fill, csr, N_EDGES);

    const int NBLK = (N_NODES + 63) / 64;  // 782

    // ---- conv1: h1 = relu(Â (x@W1) + b1), aggregate in 64-d ----
    k_gemm_tile<128, 64, false><<<dim3(NBLK, 1), 256, 0, stream>>>(x, W1, nullptr, bufA, N_NODES);
    k_agg64<true><<<(N_NODES + 3) / 4, 256, 0, stream>>>(bufA, dinv, row_ptr, csr, b1, bufB, N_NODES);

    // ---- conv2: h2 = relu((Â h1)@W2 + b2) — aggregate FIRST (64-d), then GEMM ----
    k_agg64<false><<<(N_NODES + 3) / 4, 256, 0, stream>>>(bufB, dinv, row_ptr, csr, nullptr, bufA, N_NODES);
    k_gemm_tile<64, 128, true><<<dim3(NBLK, 2), 256, 0, stream>>>(bufA, W2, b2, bufB, N_NODES);

    // ---- pool + MLP ----
    k_pool<<<(N_NODES + 63) / 64, 128, 0, stream>>>(bufB, bat, sums, cnt, N_NODES);
    k_mlp<<<N_GRAPHS, 128, 0, stream>>>(sums, cnt, M1, c1, M2, c2, M3, c3, M4, c4, out);
}

// Round 6
// 317.019 us; speedup vs baseline: 8.2431x; 1.0398x over previous
//
#include <hip/hip_runtime.h>

#define N_NODES 50000
#define N_EDGES 800000
#define N_GRAPHS 64

#define SCAN_BLOCK 256
#define SCAN_ITEMS 4
#define SCAN_CHUNK (SCAN_BLOCK * SCAN_ITEMS)                  // 1024
#define NB_SCAN ((N_NODES + SCAN_CHUNK - 1) / SCAN_CHUNK)     // 49

#define FILL_STRIPES 256   // blocks per node-range; grid = 8*FILL_STRIPES

// ---------------- CSR build ----------------

__global__ void k_deg_edges(const int* __restrict__ dst, int* __restrict__ deg, int E) {
    int i = blockIdx.x * blockDim.x + threadIdx.x;
    if (i < E) atomicAdd(&deg[dst[i]], 1);
}

__global__ void k_scan1(const int* __restrict__ deg, int* __restrict__ part) {
    __shared__ int lds[SCAN_BLOCK];
    int b = blockIdx.x, t = threadIdx.x;
    int base = b * SCAN_CHUNK + t * SCAN_ITEMS;
    int s = 0;
#pragma unroll
    for (int k = 0; k < SCAN_ITEMS; ++k) {
        int i = base + k;
        if (i < N_NODES) s += deg[i];
    }
    lds[t] = s;
    __syncthreads();
    for (int off = SCAN_BLOCK / 2; off > 0; off >>= 1) {
        if (t < off) lds[t] += lds[t + off];
        __syncthreads();
    }
    if (t == 0) part[b] = lds[0];
}

__global__ void k_scan2(int* part, int* row_ptr) {
    int run = 0;
    for (int i = 0; i < NB_SCAN; ++i) { int v = part[i]; part[i] = run; run += v; }
    row_ptr[N_NODES] = run;
}

__global__ void k_scan3(const int* __restrict__ deg, const int* __restrict__ part,
                        int* __restrict__ row_ptr, int* __restrict__ fill,
                        float* __restrict__ dinv) {
    __shared__ int lds[SCAN_BLOCK];
    int b = blockIdx.x, t = threadIdx.x;
    int base = b * SCAN_CHUNK + t * SCAN_ITEMS;
    int v[SCAN_ITEMS];
    int s = 0;
#pragma unroll
    for (int k = 0; k < SCAN_ITEMS; ++k) {
        int i = base + k;
        v[k] = (i < N_NODES) ? deg[i] : 0;
        s += v[k];
    }
    lds[t] = s;
    __syncthreads();
    for (int off = 1; off < SCAN_BLOCK; off <<= 1) {
        int val = (t >= off) ? lds[t - off] : 0;
        __syncthreads();
        lds[t] += val;
        __syncthreads();
    }
    int excl = (t == 0 ? 0 : lds[t - 1]) + part[b];
#pragma unroll
    for (int k = 0; k < SCAN_ITEMS; ++k) {
        int i = base + k;
        if (i < N_NODES) {
            row_ptr[i] = excl;
            fill[i] = excl;
            dinv[i] = rsqrtf((float)(v[k] + 1));  // +1 self loop
            excl += v[k];
        }
    }
}

// XCD-partitioned fill: block handles node-range (blockIdx%8); each range's csr
// slice is contiguous -> written by (hopefully) one XCD -> full-line writebacks.
// Correct regardless of the actual blockIdx->XCD mapping.
__global__ void k_fill_part(const int* __restrict__ src, const int* __restrict__ dst,
                            int* __restrict__ fill, int* __restrict__ csr, int E) {
    const int range = blockIdx.x & 7;
    const int stripe = blockIdx.x >> 3;
    const int lo = range * (N_NODES / 8);
    const int hi = lo + (N_NODES / 8);
    for (int e = stripe * 256 + threadIdx.x; e < E; e += FILL_STRIPES * 256) {
        int d = dst[e];
        if (d >= lo && d < hi) {
            int pos = atomicAdd(&fill[d], 1);
            csr[pos] = src[e];
        }
    }
}

// ---------------- register-blocked GEMM ----------------
// C[N,WS](col slice coff..coff+63) = A[N,FIN] @ W[FIN,WS](cols coff..coff+63)
// 64 rows x 64 cols per block, 256 threads, 4x4 micro-tile per thread.
// RELU: C = relu(C + bias). SCALE: C *= dscale[row] (dinv pre-fold).

template <int FIN, int WS, bool RELU, bool SCALE>
__global__ __launch_bounds__(256) void k_gemm_tile(const float* __restrict__ A,
                                                   const float* __restrict__ W,
                                                   const float* __restrict__ bias,
                                                   const float* __restrict__ dscale,
                                                   float* __restrict__ C, int N) {
    __shared__ __align__(16) float As[64 * (FIN + 2)];
    __shared__ __align__(16) float Wsm[FIN * 64];
    const int t = threadIdx.x;
    const int row0 = blockIdx.x * 64;
    const int coff = blockIdx.y * 64;

    const int NF4 = 64 * FIN / 4;
    for (int idx = t; idx < NF4; idx += 256) {
        int r = idx / (FIN / 4);
        int c4 = idx % (FIN / 4);
        float4 v = make_float4(0.f, 0.f, 0.f, 0.f);
        if (row0 + r < N) v = ((const float4*)(A + (size_t)(row0 + r) * FIN))[c4];
        float* p = &As[r * (FIN + 2) + c4 * 4];
        ((float2*)p)[0] = make_float2(v.x, v.y);
        ((float2*)p)[1] = make_float2(v.z, v.w);
    }
    for (int idx = t; idx < FIN * 16; idx += 256) {
        int r = idx / 16, c4 = idx % 16;
        float4 v = ((const float4*)(W + (size_t)r * WS + coff))[c4];
        *((float4*)&Wsm[r * 64 + c4 * 4]) = v;
    }
    __syncthreads();

    const int tc = (t & 15) * 4;
    const int tr = (t >> 4) * 4;
    float acc[4][4] = {};
#pragma unroll 4
    for (int k = 0; k < FIN; k += 2) {
        float2 a[4];
#pragma unroll
        for (int r = 0; r < 4; ++r)
            a[r] = *(const float2*)&As[(tr + r) * (FIN + 2) + k];
        float4 w0 = *(const float4*)&Wsm[k * 64 + tc];
        float4 w1 = *(const float4*)&Wsm[(k + 1) * 64 + tc];
#pragma unroll
        for (int r = 0; r < 4; ++r) {
            acc[r][0] = fmaf(a[r].x, w0.x, acc[r][0]);
            acc[r][1] = fmaf(a[r].x, w0.y, acc[r][1]);
            acc[r][2] = fmaf(a[r].x, w0.z, acc[r][2]);
            acc[r][3] = fmaf(a[r].x, w0.w, acc[r][3]);
            acc[r][0] = fmaf(a[r].y, w1.x, acc[r][0]);
            acc[r][1] = fmaf(a[r].y, w1.y, acc[r][1]);
            acc[r][2] = fmaf(a[r].y, w1.z, acc[r][2]);
            acc[r][3] = fmaf(a[r].y, w1.w, acc[r][3]);
        }
    }

    float4 bv = make_float4(0.f, 0.f, 0.f, 0.f);
    if (RELU) bv = *(const float4*)&bias[coff + tc];
#pragma unroll
    for (int r = 0; r < 4; ++r) {
        int row = row0 + tr + r;
        if (row < N) {
            float4 v = make_float4(acc[r][0], acc[r][1], acc[r][2], acc[r][3]);
            if (RELU) {
                v.x = fmaxf(v.x + bv.x, 0.f);
                v.y = fmaxf(v.y + bv.y, 0.f);
                v.z = fmaxf(v.z + bv.z, 0.f);
                v.w = fmaxf(v.w + bv.w, 0.f);
            }
            if (SCALE) {
                float s = dscale[row];
                v.x *= s; v.y *= s; v.z *= s; v.w *= s;
            }
            *((float4*)(C + (size_t)row * WS + coff + tc)) = v;
        }
    }
}

// ---------------- 64-wide aggregate (gather, no atomics) ----------------
// Input h is PRE-SCALED by dinv (h̃). sum = h̃[n] + Σ_s h̃[s].
// RELU (conv1): out = dinv[n] * relu(bias + dinv[n]*sum)   [stores h̃1]
// else (conv2): out = dinv[n] * sum                         [z, GEMM2 input]

template <bool RELU>
__global__ void k_agg64(const float* __restrict__ h, const float* __restrict__ dinv,
                        const int* __restrict__ row_ptr, const int* __restrict__ csr,
                        const float* __restrict__ bias, float* __restrict__ out, int N) {
    int node = blockIdx.x * 4 + (threadIdx.x >> 6);  // one wave per node
    int f = threadIdx.x & 63;
    if (node >= N) return;
    float di = dinv[node];
    float acc0 = h[(size_t)node * 64 + f];  // self loop (pre-scaled)
    float acc1 = 0.f, acc2 = 0.f, acc3 = 0.f;
    int beg = row_ptr[node], end = row_ptr[node + 1];
    int j = beg;
    for (; j + 4 <= end; j += 4) {
        int s0 = csr[j], s1 = csr[j + 1], s2 = csr[j + 2], s3 = csr[j + 3];
        acc0 += h[(size_t)s0 * 64 + f];
        acc1 += h[(size_t)s1 * 64 + f];
        acc2 += h[(size_t)s2 * 64 + f];
        acc3 += h[(size_t)s3 * 64 + f];
    }
    for (; j < end; ++j) acc0 += h[(size_t)csr[j] * 64 + f];
    float acc = (acc0 + acc1) + (acc2 + acc3);
    if (RELU) {
        float v = fmaf(acc, di, bias[f]);
        out[(size_t)node * 64 + f] = di * (v > 0.f ? v : 0.f);
    } else {
        out[(size_t)node * 64 + f] = acc * di;
    }
}

// ---------------- global mean pool + counts (batch is sorted) ----------------

__global__ void k_pool(const float* __restrict__ h, const int* __restrict__ batch,
                       float* __restrict__ sums, float* __restrict__ cnt, int N) {
    int n0 = blockIdx.x * 64;
    int f = threadIdx.x;  // 128 threads = one feature each
    int end = min(n0 + 64, N);
    int cur = batch[n0];
    float acc = 0.f, acc_c = 0.f;
    for (int n = n0; n < end; ++n) {
        int g = batch[n];
        float v = h[(size_t)n * 128 + f];
        if (g != cur) {
            atomicAdd(&sums[cur * 128 + f], acc);
            if (f == 0) atomicAdd(&cnt[cur], acc_c);
            acc = 0.f; acc_c = 0.f;
            cur = g;
        }
        acc += v;
        acc_c += 1.f;
    }
    atomicAdd(&sums[cur * 128 + f], acc);
    if (f == 0) atomicAdd(&cnt[cur], acc_c);
}

// ---------------- MLP head: one block per graph ----------------

__global__ void k_mlp(const float* __restrict__ sums, const float* __restrict__ cnt,
                      const float* __restrict__ M1, const float* __restrict__ c1,
                      const float* __restrict__ M2, const float* __restrict__ c2,
                      const float* __restrict__ M3, const float* __restrict__ c3,
                      const float* __restrict__ M4, const float* __restrict__ c4,
                      float* __restrict__ out) {
    __shared__ float g[128], t1[64], t2[64], t3[64];
    int b = blockIdx.x;
    int t = threadIdx.x;
    if (t < 128) g[t] = sums[b * 128 + t] / fmaxf(cnt[b], 1.0f);
    __syncthreads();
    if (t < 64) {
        float acc = c1[t];
        for (int k = 0; k < 128; ++k) acc = fmaf(g[k], M1[k * 64 + t], acc);
        t1[t] = acc >= 0.f ? acc : 0.2f * acc;
    }
    __syncthreads();
    if (t < 64) {
        float acc = c2[t];
        for (int k = 0; k < 64; ++k) acc = fmaf(t1[k], M2[k * 64 + t], acc);
        t2[t] = acc >= 0.f ? acc : 0.1f * acc;
    }
    __syncthreads();
    if (t < 64) {
        float acc = c3[t];
        for (int k = 0; k < 64; ++k) acc = fmaf(t2[k], M3[k * 64 + t], acc);
        t3[t] = acc >= 0.f ? acc : 0.1f * acc;
    }
    __syncthreads();
    if (t == 0) {
        float acc = c4[0];
        for (int k = 0; k < 64; ++k) acc = fmaf(t3[k], M4[k], acc);
        out[b] = fmaxf(acc, 0.f);
    }
}

// ---------------- launch ----------------

extern "C" void kernel_launch(void* const* d_in, const int* in_sizes, int n_in,
                              void* d_out, int out_size, void* d_ws, size_t ws_size,
                              hipStream_t stream) {
    const float* x   = (const float*)d_in[0];
    const int*   ei  = (const int*)d_in[1];
    const int*   bat = (const int*)d_in[2];
    const float* W1  = (const float*)d_in[3];
    const float* b1  = (const float*)d_in[4];
    const float* W2  = (const float*)d_in[5];
    const float* b2  = (const float*)d_in[6];
    const float* M1  = (const float*)d_in[7];
    const float* c1  = (const float*)d_in[8];
    const float* M2  = (const float*)d_in[9];
    const float* c2  = (const float*)d_in[10];
    const float* M3  = (const float*)d_in[11];
    const float* c3  = (const float*)d_in[12];
    const float* M4  = (const float*)d_in[13];
    const float* c4  = (const float*)d_in[14];
    float* out = (float*)d_out;

    const int* src = ei;            // edge_index[0]
    const int* dst = ei + N_EDGES;  // edge_index[1]

    // workspace layout
    float* bufA    = (float*)d_ws;                          // N*128 f
    float* bufB    = bufA + (size_t)N_NODES * 128;          // N*128 f
    float* dinv    = bufB + (size_t)N_NODES * 128;          // N f
    float* sums    = dinv + N_NODES;                        // 64*128 f
    float* cnt     = sums + N_GRAPHS * 128;                 // 64 f
    int*   deg     = (int*)(cnt + N_GRAPHS);                // N i
    int*   row_ptr = deg + N_NODES;                         // N+1 i
    int*   fill    = row_ptr + N_NODES + 1;                 // N i
    int*   part    = fill + N_NODES;                        // 64 i
    int*   csr     = part + 64;                             // E i

    // ---- CSR build + normalization ----
    hipMemsetAsync(deg, 0, N_NODES * sizeof(int), stream);
    hipMemsetAsync(sums, 0, (N_GRAPHS * 128 + N_GRAPHS) * sizeof(float), stream);
    k_deg_edges<<<(N_EDGES + 255) / 256, 256, 0, stream>>>(dst, deg, N_EDGES);
    k_scan1<<<NB_SCAN, SCAN_BLOCK, 0, stream>>>(deg, part);
    k_scan2<<<1, 1, 0, stream>>>(part, row_ptr);
    k_scan3<<<NB_SCAN, SCAN_BLOCK, 0, stream>>>(deg, part, row_ptr, fill, dinv);
    k_fill_part<<<8 * FILL_STRIPES, 256, 0, stream>>>(src, dst, fill, csr, N_EDGES);

    const int NBLK = (N_NODES + 63) / 64;  // 782

    // ---- conv1: g̃ = dinv ⊙ (x@W1); h̃1 = dinv ⊙ relu(Â-sum + b1) ----
    k_gemm_tile<128, 64, false, true><<<dim3(NBLK, 1), 256, 0, stream>>>(x, W1, nullptr, dinv, bufA, N_NODES);
    k_agg64<true><<<(N_NODES + 3) / 4, 256, 0, stream>>>(bufA, dinv, row_ptr, csr, b1, bufB, N_NODES);

    // ---- conv2: z = dinv ⊙ (Σ h̃1); h2 = relu(z@W2 + b2) ----
    k_agg64<false><<<(N_NODES + 3) / 4, 256, 0, stream>>>(bufB, dinv, row_ptr, csr, nullptr, bufA, N_NODES);
    k_gemm_tile<64, 128, true, false><<<dim3(NBLK, 2), 256, 0, stream>>>(bufA, W2, b2, nullptr, bufB, N_NODES);

    // ---- pool + MLP ----
    k_pool<<<(N_NODES + 63) / 64, 128, 0, stream>>>(bufB, bat, sums, cnt, N_NODES);
    k_mlp<<<N_GRAPHS, 128, 0, stream>>>(sums, cnt, M1, c1, M2, c2, M3, c3, M4, c4, out);
}

// Round 7
// 289.983 us; speedup vs baseline: 9.0116x; 1.0932x over previous
//
#include <hip/hip_runtime.h>
#include <hip/hip_fp16.h>

#define N_NODES 50000
#define N_EDGES 800000
#define N_GRAPHS 64

#define SCAN_BLOCK 256
#define SCAN_ITEMS 4
#define SCAN_CHUNK (SCAN_BLOCK * SCAN_ITEMS)                  // 1024
#define NB_SCAN ((N_NODES + SCAN_CHUNK - 1) / SCAN_CHUNK)     // 49

#define FILL_STRIPES 256   // blocks per node-range; grid = 8*FILL_STRIPES

// ---------------- CSR build ----------------

__global__ void k_deg_edges(const int* __restrict__ dst, int* __restrict__ deg, int E) {
    int i = blockIdx.x * blockDim.x + threadIdx.x;
    if (i < E) atomicAdd(&deg[dst[i]], 1);
}

__global__ void k_scan1(const int* __restrict__ deg, int* __restrict__ part) {
    __shared__ int lds[SCAN_BLOCK];
    int b = blockIdx.x, t = threadIdx.x;
    int base = b * SCAN_CHUNK + t * SCAN_ITEMS;
    int s = 0;
#pragma unroll
    for (int k = 0; k < SCAN_ITEMS; ++k) {
        int i = base + k;
        if (i < N_NODES) s += deg[i];
    }
    lds[t] = s;
    __syncthreads();
    for (int off = SCAN_BLOCK / 2; off > 0; off >>= 1) {
        if (t < off) lds[t] += lds[t + off];
        __syncthreads();
    }
    if (t == 0) part[b] = lds[0];
}

__global__ void k_scan2(int* part, int* row_ptr) {
    int run = 0;
    for (int i = 0; i < NB_SCAN; ++i) { int v = part[i]; part[i] = run; run += v; }
    row_ptr[N_NODES] = run;
}

__global__ void k_scan3(const int* __restrict__ deg, const int* __restrict__ part,
                        int* __restrict__ row_ptr, int* __restrict__ fill,
                        float* __restrict__ dinv) {
    __shared__ int lds[SCAN_BLOCK];
    int b = blockIdx.x, t = threadIdx.x;
    int base = b * SCAN_CHUNK + t * SCAN_ITEMS;
    int v[SCAN_ITEMS];
    int s = 0;
#pragma unroll
    for (int k = 0; k < SCAN_ITEMS; ++k) {
        int i = base + k;
        v[k] = (i < N_NODES) ? deg[i] : 0;
        s += v[k];
    }
    lds[t] = s;
    __syncthreads();
    for (int off = 1; off < SCAN_BLOCK; off <<= 1) {
        int val = (t >= off) ? lds[t - off] : 0;
        __syncthreads();
        lds[t] += val;
        __syncthreads();
    }
    int excl = (t == 0 ? 0 : lds[t - 1]) + part[b];
#pragma unroll
    for (int k = 0; k < SCAN_ITEMS; ++k) {
        int i = base + k;
        if (i < N_NODES) {
            row_ptr[i] = excl;
            fill[i] = excl;
            dinv[i] = rsqrtf((float)(v[k] + 1));  // +1 self loop
            excl += v[k];
        }
    }
}

// XCD-partitioned fill (R6 win: contiguous csr slice per node-range -> full-line
// writebacks). csr values as ushort (src < 65536) halves write volume.
__global__ void k_fill_part(const int* __restrict__ src, const int* __restrict__ dst,
                            int* __restrict__ fill, unsigned short* __restrict__ csr, int E) {
    const int range = blockIdx.x & 7;
    const int stripe = blockIdx.x >> 3;
    const int lo = range * (N_NODES / 8);
    const int hi = lo + (N_NODES / 8);
    for (int e = stripe * 256 + threadIdx.x; e < E; e += FILL_STRIPES * 256) {
        int d = dst[e];
        if (d >= lo && d < hi) {
            int pos = atomicAdd(&fill[d], 1);
            csr[pos] = (unsigned short)src[e];
        }
    }
}

// ---------------- register-blocked GEMM ----------------
// 64 rows x 64 cols per block, 256 threads, 4x4 micro-tile per thread.
// RELU: C = relu(C + bias). SCALE: C *= dscale[row].
// HALF_OUT: store C as fp16 (row stride WS halves).

template <int FIN, int WS, bool RELU, bool SCALE, bool HALF_OUT>
__global__ __launch_bounds__(256) void k_gemm_tile(const float* __restrict__ A,
                                                   const float* __restrict__ W,
                                                   const float* __restrict__ bias,
                                                   const float* __restrict__ dscale,
                                                   void* __restrict__ Cout, int N) {
    __shared__ __align__(16) float As[64 * (FIN + 2)];
    __shared__ __align__(16) float Wsm[FIN * 64];
    const int t = threadIdx.x;
    const int row0 = blockIdx.x * 64;
    const int coff = blockIdx.y * 64;

    const int NF4 = 64 * FIN / 4;
    for (int idx = t; idx < NF4; idx += 256) {
        int r = idx / (FIN / 4);
        int c4 = idx % (FIN / 4);
        float4 v = make_float4(0.f, 0.f, 0.f, 0.f);
        if (row0 + r < N) v = ((const float4*)(A + (size_t)(row0 + r) * FIN))[c4];
        float* p = &As[r * (FIN + 2) + c4 * 4];
        ((float2*)p)[0] = make_float2(v.x, v.y);
        ((float2*)p)[1] = make_float2(v.z, v.w);
    }
    for (int idx = t; idx < FIN * 16; idx += 256) {
        int r = idx / 16, c4 = idx % 16;
        float4 v = ((const float4*)(W + (size_t)r * WS + coff))[c4];
        *((float4*)&Wsm[r * 64 + c4 * 4]) = v;
    }
    __syncthreads();

    const int tc = (t & 15) * 4;
    const int tr = (t >> 4) * 4;
    float acc[4][4] = {};
#pragma unroll 4
    for (int k = 0; k < FIN; k += 2) {
        float2 a[4];
#pragma unroll
        for (int r = 0; r < 4; ++r)
            a[r] = *(const float2*)&As[(tr + r) * (FIN + 2) + k];
        float4 w0 = *(const float4*)&Wsm[k * 64 + tc];
        float4 w1 = *(const float4*)&Wsm[(k + 1) * 64 + tc];
#pragma unroll
        for (int r = 0; r < 4; ++r) {
            acc[r][0] = fmaf(a[r].x, w0.x, acc[r][0]);
            acc[r][1] = fmaf(a[r].x, w0.y, acc[r][1]);
            acc[r][2] = fmaf(a[r].x, w0.z, acc[r][2]);
            acc[r][3] = fmaf(a[r].x, w0.w, acc[r][3]);
            acc[r][0] = fmaf(a[r].y, w1.x, acc[r][0]);
            acc[r][1] = fmaf(a[r].y, w1.y, acc[r][1]);
            acc[r][2] = fmaf(a[r].y, w1.z, acc[r][2]);
            acc[r][3] = fmaf(a[r].y, w1.w, acc[r][3]);
        }
    }

    float4 bv = make_float4(0.f, 0.f, 0.f, 0.f);
    if (RELU) bv = *(const float4*)&bias[coff + tc];
#pragma unroll
    for (int r = 0; r < 4; ++r) {
        int row = row0 + tr + r;
        if (row < N) {
            float4 v = make_float4(acc[r][0], acc[r][1], acc[r][2], acc[r][3]);
            if (RELU) {
                v.x = fmaxf(v.x + bv.x, 0.f);
                v.y = fmaxf(v.y + bv.y, 0.f);
                v.z = fmaxf(v.z + bv.z, 0.f);
                v.w = fmaxf(v.w + bv.w, 0.f);
            }
            if (SCALE) {
                float s = dscale[row];
                v.x *= s; v.y *= s; v.z *= s; v.w *= s;
            }
            if (HALF_OUT) {
                __half2* dsth = (__half2*)((__half*)Cout + (size_t)row * WS + coff + tc);
                dsth[0] = __floats2half2_rn(v.x, v.y);
                dsth[1] = __floats2half2_rn(v.z, v.w);
            } else {
                *((float4*)((float*)Cout + (size_t)row * WS + coff + tc)) = v;
            }
        }
    }
}

// ---------------- 64-wide aggregate, fp16 input, half-wave per node ----------------
// Input h is pre-scaled by dinv (h̃, fp16). 32 lanes/node, __half2 per lane.
// RELU (conv1): out(fp16) = dinv[n] * relu(bias + dinv[n]*sum)
// else (conv2): out(fp32) = dinv[n] * sum

template <bool RELU>
__global__ void k_agg_h(const __half2* __restrict__ h, const float* __restrict__ dinv,
                        const int* __restrict__ row_ptr, const unsigned short* __restrict__ csr,
                        const float* __restrict__ bias, void* __restrict__ out, int N) {
    int node = blockIdx.x * 8 + (threadIdx.x >> 5);  // half-wave per node
    int fp = threadIdx.x & 31;                       // feature-pair index
    if (node >= N) return;
    float di = dinv[node];
    float2 sv = __half22float2(h[(size_t)node * 32 + fp]);  // self loop (pre-scaled)
    float ax0 = sv.x, ay0 = sv.y;
    float ax1 = 0.f, ay1 = 0.f, ax2 = 0.f, ay2 = 0.f, ax3 = 0.f, ay3 = 0.f;
    int beg = row_ptr[node], end = row_ptr[node + 1];
    int j = beg;
    for (; j + 4 <= end; j += 4) {
        int s0 = csr[j], s1 = csr[j + 1], s2 = csr[j + 2], s3 = csr[j + 3];
        float2 v0 = __half22float2(h[(size_t)s0 * 32 + fp]);
        float2 v1 = __half22float2(h[(size_t)s1 * 32 + fp]);
        float2 v2 = __half22float2(h[(size_t)s2 * 32 + fp]);
        float2 v3 = __half22float2(h[(size_t)s3 * 32 + fp]);
        ax0 += v0.x; ay0 += v0.y;
        ax1 += v1.x; ay1 += v1.y;
        ax2 += v2.x; ay2 += v2.y;
        ax3 += v3.x; ay3 += v3.y;
    }
    for (; j < end; ++j) {
        float2 v = __half22float2(h[(size_t)csr[j] * 32 + fp]);
        ax0 += v.x; ay0 += v.y;
    }
    float ax = (ax0 + ax1) + (ax2 + ax3);
    float ay = (ay0 + ay1) + (ay2 + ay3);
    if (RELU) {
        float2 b = ((const float2*)bias)[fp];
        float vx = fmaf(ax, di, b.x);
        float vy = fmaf(ay, di, b.y);
        vx = vx > 0.f ? vx : 0.f;
        vy = vy > 0.f ? vy : 0.f;
        ((__half2*)out)[(size_t)node * 32 + fp] = __floats2half2_rn(di * vx, di * vy);
    } else {
        ((float2*)out)[(size_t)node * 32 + fp] = make_float2(ax * di, ay * di);
    }
}

// ---------------- global mean pool + counts (batch is sorted) ----------------

__global__ void k_pool(const float* __restrict__ h, const int* __restrict__ batch,
                       float* __restrict__ sums, float* __restrict__ cnt, int N) {
    int n0 = blockIdx.x * 64;
    int f = threadIdx.x;  // 128 threads = one feature each
    int end = min(n0 + 64, N);
    int cur = batch[n0];
    float acc = 0.f, acc_c = 0.f;
    for (int n = n0; n < end; ++n) {
        int g = batch[n];
        float v = h[(size_t)n * 128 + f];
        if (g != cur) {
            atomicAdd(&sums[cur * 128 + f], acc);
            if (f == 0) atomicAdd(&cnt[cur], acc_c);
            acc = 0.f; acc_c = 0.f;
            cur = g;
        }
        acc += v;
        acc_c += 1.f;
    }
    atomicAdd(&sums[cur * 128 + f], acc);
    if (f == 0) atomicAdd(&cnt[cur], acc_c);
}

// ---------------- MLP head: one block per graph ----------------

__global__ void k_mlp(const float* __restrict__ sums, const float* __restrict__ cnt,
                      const float* __restrict__ M1, const float* __restrict__ c1,
                      const float* __restrict__ M2, const float* __restrict__ c2,
                      const float* __restrict__ M3, const float* __restrict__ c3,
                      const float* __restrict__ M4, const float* __restrict__ c4,
                      float* __restrict__ out) {
    __shared__ float g[128], t1[64], t2[64], t3[64];
    int b = blockIdx.x;
    int t = threadIdx.x;
    if (t < 128) g[t] = sums[b * 128 + t] / fmaxf(cnt[b], 1.0f);
    __syncthreads();
    if (t < 64) {
        float acc = c1[t];
        for (int k = 0; k < 128; ++k) acc = fmaf(g[k], M1[k * 64 + t], acc);
        t1[t] = acc >= 0.f ? acc : 0.2f * acc;
    }
    __syncthreads();
    if (t < 64) {
        float acc = c2[t];
        for (int k = 0; k < 64; ++k) acc = fmaf(t1[k], M2[k * 64 + t], acc);
        t2[t] = acc >= 0.f ? acc : 0.1f * acc;
    }
    __syncthreads();
    if (t < 64) {
        float acc = c3[t];
        for (int k = 0; k < 64; ++k) acc = fmaf(t2[k], M3[k * 64 + t], acc);
        t3[t] = acc >= 0.f ? acc : 0.1f * acc;
    }
    __syncthreads();
    if (t == 0) {
        float acc = c4[0];
        for (int k = 0; k < 64; ++k) acc = fmaf(t3[k], M4[k], acc);
        out[b] = fmaxf(acc, 0.f);
    }
}

// ---------------- launch ----------------

extern "C" void kernel_launch(void* const* d_in, const int* in_sizes, int n_in,
                              void* d_out, int out_size, void* d_ws, size_t ws_size,
                              hipStream_t stream) {
    const float* x   = (const float*)d_in[0];
    const int*   ei  = (const int*)d_in[1];
    const int*   bat = (const int*)d_in[2];
    const float* W1  = (const float*)d_in[3];
    const float* b1  = (const float*)d_in[4];
    const float* W2  = (const float*)d_in[5];
    const float* b2  = (const float*)d_in[6];
    const float* M1  = (const float*)d_in[7];
    const float* c1  = (const float*)d_in[8];
    const float* M2  = (const float*)d_in[9];
    const float* c2  = (const float*)d_in[10];
    const float* M3  = (const float*)d_in[11];
    const float* c3  = (const float*)d_in[12];
    const float* M4  = (const float*)d_in[13];
    const float* c4  = (const float*)d_in[14];
    float* out = (float*)d_out;

    const int* src = ei;            // edge_index[0]
    const int* dst = ei + N_EDGES;  // edge_index[1]

    // workspace layout (bufA/bufB are reused with different dtypes per phase)
    float* bufA    = (float*)d_ws;                          // N*128 f
    float* bufB    = bufA + (size_t)N_NODES * 128;          // N*128 f
    float* dinv    = bufB + (size_t)N_NODES * 128;          // N f
    float* sums    = dinv + N_NODES;                        // 64*128 f
    float* cnt     = sums + N_GRAPHS * 128;                 // 64 f
    int*   deg     = (int*)(cnt + N_GRAPHS);                // N i
    int*   row_ptr = deg + N_NODES;                         // N+1 i
    int*   fill    = row_ptr + N_NODES + 1;                 // N i
    int*   part    = fill + N_NODES;                        // 64 i
    unsigned short* csr = (unsigned short*)(part + 64);     // E u16

    // ---- CSR build + normalization ----
    hipMemsetAsync(deg, 0, N_NODES * sizeof(int), stream);
    hipMemsetAsync(sums, 0, (N_GRAPHS * 128 + N_GRAPHS) * sizeof(float), stream);
    k_deg_edges<<<(N_EDGES + 255) / 256, 256, 0, stream>>>(dst, deg, N_EDGES);
    k_scan1<<<NB_SCAN, SCAN_BLOCK, 0, stream>>>(deg, part);
    k_scan2<<<1, 1, 0, stream>>>(part, row_ptr);
    k_scan3<<<NB_SCAN, SCAN_BLOCK, 0, stream>>>(deg, part, row_ptr, fill, dinv);
    k_fill_part<<<8 * FILL_STRIPES, 256, 0, stream>>>(src, dst, fill, csr, N_EDGES);

    const int NBLK = (N_NODES + 63) / 64;   // 782
    const int ABLK = (N_NODES + 7) / 8;     // 6250

    // ---- conv1: g̃(fp16) = dinv ⊙ (x@W1); h̃1(fp16) = dinv ⊙ relu(Â-sum + b1) ----
    k_gemm_tile<128, 64, false, true, true><<<dim3(NBLK, 1), 256, 0, stream>>>(
        x, W1, nullptr, dinv, bufA, N_NODES);
    k_agg_h<true><<<ABLK, 256, 0, stream>>>(
        (const __half2*)bufA, dinv, row_ptr, csr, b1, bufB, N_NODES);

    // ---- conv2: z(fp32) = dinv ⊙ (Σ h̃1); h2 = relu(z@W2 + b2) ----
    k_agg_h<false><<<ABLK, 256, 0, stream>>>(
        (const __half2*)bufB, dinv, row_ptr, csr, nullptr, bufA, N_NODES);
    k_gemm_tile<64, 128, true, false, false><<<dim3(NBLK, 2), 256, 0, stream>>>(
        bufA, W2, b2, nullptr, bufB, N_NODES);

    // ---- pool + MLP ----
    k_pool<<<(N_NODES + 63) / 64, 128, 0, stream>>>(bufB, bat, sums, cnt, N_NODES);
    k_mlp<<<N_GRAPHS, 128, 0, stream>>>(sums, cnt, M1, c1, M2, c2, M3, c3, M4, c4, out);
}

// Round 8
// 274.425 us; speedup vs baseline: 9.5225x; 1.0567x over previous
//
#include <hip/hip_runtime.h>
#include <hip/hip_fp16.h>

#define N_NODES 50000
#define N_EDGES 800000
#define N_GRAPHS 64

#define SCAN_BLOCK 256
#define SCAN_ITEMS 4
#define SCAN_CHUNK (SCAN_BLOCK * SCAN_ITEMS)                  // 1024
#define NB_SCAN ((N_NODES + SCAN_CHUNK - 1) / SCAN_CHUNK)     // 49

#define FILL_STRIPES 256   // blocks per node-range; grid = 8*FILL_STRIPES

// ---------------- CSR build ----------------

// XCD-partitioned degree count: deg[] lines stay (mostly) XCD-local.
__global__ void k_deg_part(const int* __restrict__ dst, int* __restrict__ deg, int E) {
    const int range = blockIdx.x & 7;
    const int stripe = blockIdx.x >> 3;
    const int lo = range * (N_NODES / 8);
    const int hi = lo + (N_NODES / 8);
    for (int e = stripe * 256 + threadIdx.x; e < E; e += FILL_STRIPES * 256) {
        int d = dst[e];
        if (d >= lo && d < hi) atomicAdd(&deg[d], 1);
    }
}

__global__ void k_scan1(const int* __restrict__ deg, int* __restrict__ part) {
    __shared__ int lds[SCAN_BLOCK];
    int b = blockIdx.x, t = threadIdx.x;
    int base = b * SCAN_CHUNK + t * SCAN_ITEMS;
    int s = 0;
#pragma unroll
    for (int k = 0; k < SCAN_ITEMS; ++k) {
        int i = base + k;
        if (i < N_NODES) s += deg[i];
    }
    lds[t] = s;
    __syncthreads();
    for (int off = SCAN_BLOCK / 2; off > 0; off >>= 1) {
        if (t < off) lds[t] += lds[t + off];
        __syncthreads();
    }
    if (t == 0) part[b] = lds[0];
}

__global__ void k_scan2(int* part, int* row_ptr) {
    int run = 0;
    for (int i = 0; i < NB_SCAN; ++i) { int v = part[i]; part[i] = run; run += v; }
    row_ptr[N_NODES] = run;
}

__global__ void k_scan3(const int* __restrict__ deg, const int* __restrict__ part,
                        int* __restrict__ row_ptr, int* __restrict__ fill,
                        float* __restrict__ dinv) {
    __shared__ int lds[SCAN_BLOCK];
    int b = blockIdx.x, t = threadIdx.x;
    int base = b * SCAN_CHUNK + t * SCAN_ITEMS;
    int v[SCAN_ITEMS];
    int s = 0;
#pragma unroll
    for (int k = 0; k < SCAN_ITEMS; ++k) {
        int i = base + k;
        v[k] = (i < N_NODES) ? deg[i] : 0;
        s += v[k];
    }
    lds[t] = s;
    __syncthreads();
    for (int off = 1; off < SCAN_BLOCK; off <<= 1) {
        int val = (t >= off) ? lds[t - off] : 0;
        __syncthreads();
        lds[t] += val;
        __syncthreads();
    }
    int excl = (t == 0 ? 0 : lds[t - 1]) + part[b];
#pragma unroll
    for (int k = 0; k < SCAN_ITEMS; ++k) {
        int i = base + k;
        if (i < N_NODES) {
            row_ptr[i] = excl;
            fill[i] = excl;
            dinv[i] = rsqrtf((float)(v[k] + 1));  // +1 self loop
            excl += v[k];
        }
    }
}

// XCD-partitioned fill (R6 win). csr values ushort (src < 65536).
__global__ void k_fill_part(const int* __restrict__ src, const int* __restrict__ dst,
                            int* __restrict__ fill, unsigned short* __restrict__ csr, int E) {
    const int range = blockIdx.x & 7;
    const int stripe = blockIdx.x >> 3;
    const int lo = range * (N_NODES / 8);
    const int hi = lo + (N_NODES / 8);
    for (int e = stripe * 256 + threadIdx.x; e < E; e += FILL_STRIPES * 256) {
        int d = dst[e];
        if (d >= lo && d < hi) {
            int pos = atomicAdd(&fill[d], 1);
            csr[pos] = (unsigned short)src[e];
        }
    }
}

// ---------------- GEMM1: g̃(fp16) = dinv ⊙ (x @ W1) ----------------
// 64 rows x 64 cols per block, 256 threads, 4x4 micro-tile per thread.

__global__ __launch_bounds__(256) void k_gemm1(const float* __restrict__ A,
                                               const float* __restrict__ W,
                                               const float* __restrict__ dscale,
                                               __half* __restrict__ Cout, int N) {
    const int FIN = 128;
    __shared__ __align__(16) float As[64 * (FIN + 2)];
    __shared__ __align__(16) float Wsm[FIN * 64];
    const int t = threadIdx.x;
    const int row0 = blockIdx.x * 64;

    const int NF4 = 64 * FIN / 4;
    for (int idx = t; idx < NF4; idx += 256) {
        int r = idx / (FIN / 4);
        int c4 = idx % (FIN / 4);
        float4 v = make_float4(0.f, 0.f, 0.f, 0.f);
        if (row0 + r < N) v = ((const float4*)(A + (size_t)(row0 + r) * FIN))[c4];
        float* p = &As[r * (FIN + 2) + c4 * 4];
        ((float2*)p)[0] = make_float2(v.x, v.y);
        ((float2*)p)[1] = make_float2(v.z, v.w);
    }
    for (int idx = t; idx < FIN * 16; idx += 256) {
        int r = idx / 16, c4 = idx % 16;
        *((float4*)&Wsm[r * 64 + c4 * 4]) = ((const float4*)(W + (size_t)r * 64))[c4];
    }
    __syncthreads();

    const int tc = (t & 15) * 4;
    const int tr = (t >> 4) * 4;
    float acc[4][4] = {};
#pragma unroll 4
    for (int k = 0; k < FIN; k += 2) {
        float2 a[4];
#pragma unroll
        for (int r = 0; r < 4; ++r)
            a[r] = *(const float2*)&As[(tr + r) * (FIN + 2) + k];
        float4 w0 = *(const float4*)&Wsm[k * 64 + tc];
        float4 w1 = *(const float4*)&Wsm[(k + 1) * 64 + tc];
#pragma unroll
        for (int r = 0; r < 4; ++r) {
            acc[r][0] = fmaf(a[r].x, w0.x, acc[r][0]);
            acc[r][1] = fmaf(a[r].x, w0.y, acc[r][1]);
            acc[r][2] = fmaf(a[r].x, w0.z, acc[r][2]);
            acc[r][3] = fmaf(a[r].x, w0.w, acc[r][3]);
            acc[r][0] = fmaf(a[r].y, w1.x, acc[r][0]);
            acc[r][1] = fmaf(a[r].y, w1.y, acc[r][1]);
            acc[r][2] = fmaf(a[r].y, w1.z, acc[r][2]);
            acc[r][3] = fmaf(a[r].y, w1.w, acc[r][3]);
        }
    }

#pragma unroll
    for (int r = 0; r < 4; ++r) {
        int row = row0 + tr + r;
        if (row < N) {
            float s = dscale[row];
            __half2* dsth = (__half2*)(Cout + (size_t)row * 64 + tc);
            dsth[0] = __floats2half2_rn(acc[r][0] * s, acc[r][1] * s);
            dsth[1] = __floats2half2_rn(acc[r][2] * s, acc[r][3] * s);
        }
    }
}

// ---------------- 64-wide aggregate, fp16 in/out, half-wave per node ----------------
// Input h pre-scaled by dinv (h̃). 32 lanes/node, __half2 per lane.
// RELU (conv1): out = fp16( dinv[n] * relu(bias + dinv[n]*sum) )   [h̃1]
// else (conv2): out = fp16( dinv[n] * sum )                         [z̃]

template <bool RELU>
__global__ void k_agg_h(const __half2* __restrict__ h, const float* __restrict__ dinv,
                        const int* __restrict__ row_ptr, const unsigned short* __restrict__ csr,
                        const float* __restrict__ bias, __half2* __restrict__ out, int N) {
    int node = blockIdx.x * 8 + (threadIdx.x >> 5);  // half-wave per node
    int fp = threadIdx.x & 31;                       // feature-pair index
    if (node >= N) return;
    float di = dinv[node];
    float2 sv = __half22float2(h[(size_t)node * 32 + fp]);  // self loop (pre-scaled)
    float ax0 = sv.x, ay0 = sv.y;
    float ax1 = 0.f, ay1 = 0.f, ax2 = 0.f, ay2 = 0.f, ax3 = 0.f, ay3 = 0.f;
    int beg = row_ptr[node], end = row_ptr[node + 1];
    int j = beg;
    for (; j + 4 <= end; j += 4) {
        int s0 = csr[j], s1 = csr[j + 1], s2 = csr[j + 2], s3 = csr[j + 3];
        float2 v0 = __half22float2(h[(size_t)s0 * 32 + fp]);
        float2 v1 = __half22float2(h[(size_t)s1 * 32 + fp]);
        float2 v2 = __half22float2(h[(size_t)s2 * 32 + fp]);
        float2 v3 = __half22float2(h[(size_t)s3 * 32 + fp]);
        ax0 += v0.x; ay0 += v0.y;
        ax1 += v1.x; ay1 += v1.y;
        ax2 += v2.x; ay2 += v2.y;
        ax3 += v3.x; ay3 += v3.y;
    }
    for (; j < end; ++j) {
        float2 v = __half22float2(h[(size_t)csr[j] * 32 + fp]);
        ax0 += v.x; ay0 += v.y;
    }
    float ax = (ax0 + ax1) + (ax2 + ax3);
    float ay = (ay0 + ay1) + (ay2 + ay3);
    if (RELU) {
        float2 b = ((const float2*)bias)[fp];
        float vx = fmaf(ax, di, b.x);
        float vy = fmaf(ay, di, b.y);
        vx = vx > 0.f ? vx : 0.f;
        vy = vy > 0.f ? vy : 0.f;
        out[(size_t)node * 32 + fp] = __floats2half2_rn(di * vx, di * vy);
    } else {
        out[(size_t)node * 32 + fp] = __floats2half2_rn(ax * di, ay * di);
    }
}

// ---------------- GEMM2 fused with mean-pool accumulation ----------------
// h2 = relu(z̃@W2 + b2) is never materialized: each 64x64 tile reduces its
// relu'd values per graph segment (batch sorted -> <=2 segments/tile typical)
// into sums[graph][col] with one LDS tree-reduce + 64 atomics per segment.

__global__ __launch_bounds__(256) void k_gemm_pool(const __half2* __restrict__ A2,
                                                   const float* __restrict__ W,
                                                   const float* __restrict__ bias,
                                                   const int* __restrict__ batch,
                                                   float* __restrict__ sums, int N) {
    __shared__ __align__(16) float As[64 * 66];
    __shared__ __align__(16) float Wsm[64 * 64];
    __shared__ float red[16][68];
    __shared__ int batchLDS[64];
    const int t = threadIdx.x;
    const int row0 = blockIdx.x * 64;
    const int coff = blockIdx.y * 64;

    // stage A (fp16 -> fp32): 64 rows x 32 half2
    for (int idx = t; idx < 64 * 32; idx += 256) {
        int r = idx >> 5, c2 = idx & 31;
        float2 v = make_float2(0.f, 0.f);
        if (row0 + r < N) v = __half22float2(A2[(size_t)(row0 + r) * 32 + c2]);
        *(float2*)&As[r * 66 + c2 * 2] = v;
    }
    // stage W col slice (64 x 64 of [64,128])
    for (int idx = t; idx < 64 * 16; idx += 256) {
        int r = idx >> 4, c4 = idx & 15;
        *(float4*)&Wsm[r * 64 + c4 * 4] = *(const float4*)&W[(size_t)r * 128 + coff + c4 * 4];
    }
    if (t < 64) batchLDS[t] = batch[min(row0 + t, N - 1)];
    __syncthreads();

    const int tc = (t & 15) * 4;
    const int tr = (t >> 4) * 4;
    float acc[4][4] = {};
#pragma unroll 4
    for (int k = 0; k < 64; k += 2) {
        float2 a[4];
#pragma unroll
        for (int r = 0; r < 4; ++r)
            a[r] = *(const float2*)&As[(tr + r) * 66 + k];
        float4 w0 = *(const float4*)&Wsm[k * 64 + tc];
        float4 w1 = *(const float4*)&Wsm[(k + 1) * 64 + tc];
#pragma unroll
        for (int r = 0; r < 4; ++r) {
            acc[r][0] = fmaf(a[r].x, w0.x, acc[r][0]);
            acc[r][1] = fmaf(a[r].x, w0.y, acc[r][1]);
            acc[r][2] = fmaf(a[r].x, w0.z, acc[r][2]);
            acc[r][3] = fmaf(a[r].x, w0.w, acc[r][3]);
            acc[r][0] = fmaf(a[r].y, w1.x, acc[r][0]);
            acc[r][1] = fmaf(a[r].y, w1.y, acc[r][1]);
            acc[r][2] = fmaf(a[r].y, w1.z, acc[r][2]);
            acc[r][3] = fmaf(a[r].y, w1.w, acc[r][3]);
        }
    }

    // bias + relu; invalid rows contribute 0
    float4 bv = *(const float4*)&bias[coff + tc];
    float v[4][4];
#pragma unroll
    for (int r = 0; r < 4; ++r) {
        bool valid = (row0 + tr + r) < N;
        v[r][0] = valid ? fmaxf(acc[r][0] + bv.x, 0.f) : 0.f;
        v[r][1] = valid ? fmaxf(acc[r][1] + bv.y, 0.f) : 0.f;
        v[r][2] = valid ? fmaxf(acc[r][2] + bv.z, 0.f) : 0.f;
        v[r][3] = valid ? fmaxf(acc[r][3] + bv.w, 0.f) : 0.f;
    }

    const int g0 = batchLDS[0], g1 = batchLDS[63];
    const int trg = t >> 4;
    for (int g = g0; g <= g1; ++g) {
        float p0 = 0.f, p1 = 0.f, p2 = 0.f, p3 = 0.f;
#pragma unroll
        for (int r = 0; r < 4; ++r) {
            if (batchLDS[tr + r] == g) { p0 += v[r][0]; p1 += v[r][1]; p2 += v[r][2]; p3 += v[r][3]; }
        }
        red[trg][tc + 0] = p0; red[trg][tc + 1] = p1;
        red[trg][tc + 2] = p2; red[trg][tc + 3] = p3;
        __syncthreads();
        for (int off = 8; off > 0; off >>= 1) {
            if (trg < off) {
#pragma unroll
                for (int c = 0; c < 4; ++c) red[trg][tc + c] += red[trg + off][tc + c];
            }
            __syncthreads();
        }
        if (t < 16) {
#pragma unroll
            for (int c = 0; c < 4; ++c)
                atomicAdd(&sums[g * 128 + coff + t * 4 + c], red[0][t * 4 + c]);
        }
        __syncthreads();
    }
}

// ---------------- MLP head: one block per graph (cnt via binary search) ----------------

__global__ void k_mlp(const float* __restrict__ sums, const int* __restrict__ batch, int N,
                      const float* __restrict__ M1, const float* __restrict__ c1,
                      const float* __restrict__ M2, const float* __restrict__ c2,
                      const float* __restrict__ M3, const float* __restrict__ c3,
                      const float* __restrict__ M4, const float* __restrict__ c4,
                      float* __restrict__ out) {
    __shared__ float g[128], t1[64], t2[64], t3[64];
    __shared__ float cntb;
    int b = blockIdx.x;
    int t = threadIdx.x;
    if (t == 0) {
        int lo = 0, hi = N;
        while (lo < hi) { int m = (lo + hi) >> 1; if (batch[m] < b) lo = m + 1; else hi = m; }
        int lb = lo;
        lo = 0; hi = N;
        while (lo < hi) { int m = (lo + hi) >> 1; if (batch[m] <= b) lo = m + 1; else hi = m; }
        cntb = fmaxf((float)(lo - lb), 1.0f);
    }
    __syncthreads();
    if (t < 128) g[t] = sums[b * 128 + t] / cntb;
    __syncthreads();
    if (t < 64) {
        float acc = c1[t];
        for (int k = 0; k < 128; ++k) acc = fmaf(g[k], M1[k * 64 + t], acc);
        t1[t] = acc >= 0.f ? acc : 0.2f * acc;
    }
    __syncthreads();
    if (t < 64) {
        float acc = c2[t];
        for (int k = 0; k < 64; ++k) acc = fmaf(t1[k], M2[k * 64 + t], acc);
        t2[t] = acc >= 0.f ? acc : 0.1f * acc;
    }
    __syncthreads();
    if (t < 64) {
        float acc = c3[t];
        for (int k = 0; k < 64; ++k) acc = fmaf(t2[k], M3[k * 64 + t], acc);
        t3[t] = acc >= 0.f ? acc : 0.1f * acc;
    }
    __syncthreads();
    if (t == 0) {
        float acc = c4[0];
        for (int k = 0; k < 64; ++k) acc = fmaf(t3[k], M4[k], acc);
        out[b] = fmaxf(acc, 0.f);
    }
}

// ---------------- launch ----------------

extern "C" void kernel_launch(void* const* d_in, const int* in_sizes, int n_in,
                              void* d_out, int out_size, void* d_ws, size_t ws_size,
                              hipStream_t stream) {
    const float* x   = (const float*)d_in[0];
    const int*   ei  = (const int*)d_in[1];
    const int*   bat = (const int*)d_in[2];
    const float* W1  = (const float*)d_in[3];
    const float* b1  = (const float*)d_in[4];
    const float* W2  = (const float*)d_in[5];
    const float* b2  = (const float*)d_in[6];
    const float* M1  = (const float*)d_in[7];
    const float* c1  = (const float*)d_in[8];
    const float* M2  = (const float*)d_in[9];
    const float* c2  = (const float*)d_in[10];
    const float* M3  = (const float*)d_in[11];
    const float* c3  = (const float*)d_in[12];
    const float* M4  = (const float*)d_in[13];
    const float* c4  = (const float*)d_in[14];
    float* out = (float*)d_out;

    const int* src = ei;            // edge_index[0]
    const int* dst = ei + N_EDGES;  // edge_index[1]

    // workspace layout (bufA/bufB reused as fp16 feature tables)
    float* bufA    = (float*)d_ws;                          // N*64 fp16 = N*32 f
    float* bufB    = bufA + (size_t)N_NODES * 64;           // N*64 fp16
    float* dinv    = bufB + (size_t)N_NODES * 64;           // N f
    float* sums    = dinv + N_NODES;                        // 64*128 f
    int*   deg     = (int*)(sums + N_GRAPHS * 128);         // N i
    int*   row_ptr = deg + N_NODES;                         // N+1 i
    int*   fill    = row_ptr + N_NODES + 1;                 // N i
    int*   part    = fill + N_NODES;                        // 64 i
    unsigned short* csr = (unsigned short*)(part + 64);     // E u16

    // ---- CSR build + normalization ----
    hipMemsetAsync(deg, 0, N_NODES * sizeof(int), stream);
    hipMemsetAsync(sums, 0, N_GRAPHS * 128 * sizeof(float), stream);
    k_deg_part<<<8 * FILL_STRIPES, 256, 0, stream>>>(dst, deg, N_EDGES);
    k_scan1<<<NB_SCAN, SCAN_BLOCK, 0, stream>>>(deg, part);
    k_scan2<<<1, 1, 0, stream>>>(part, row_ptr);
    k_scan3<<<NB_SCAN, SCAN_BLOCK, 0, stream>>>(deg, part, row_ptr, fill, dinv);
    k_fill_part<<<8 * FILL_STRIPES, 256, 0, stream>>>(src, dst, fill, csr, N_EDGES);

    const int NBLK = (N_NODES + 63) / 64;   // 782
    const int ABLK = (N_NODES + 7) / 8;     // 6250

    // ---- conv1: g̃(fp16) = dinv ⊙ (x@W1); h̃1(fp16) = dinv ⊙ relu(Â-sum + b1) ----
    k_gemm1<<<NBLK, 256, 0, stream>>>(x, W1, dinv, (__half*)bufA, N_NODES);
    k_agg_h<true><<<ABLK, 256, 0, stream>>>(
        (const __half2*)bufA, dinv, row_ptr, csr, b1, (__half2*)bufB, N_NODES);

    // ---- conv2: z̃(fp16) = dinv ⊙ (Σ h̃1); fused gemm2+relu+mean-pool ----
    k_agg_h<false><<<ABLK, 256, 0, stream>>>(
        (const __half2*)bufB, dinv, row_ptr, csr, nullptr, (__half2*)bufA, N_NODES);
    k_gemm_pool<<<dim3(NBLK, 2), 256, 0, stream>>>(
        (const __half2*)bufA, W2, b2, bat, sums, N_NODES);

    // ---- MLP (cnt via binary search on sorted batch) ----
    k_mlp<<<N_GRAPHS, 128, 0, stream>>>(sums, bat, N_NODES,
                                        M1, c1, M2, c2, M3, c3, M4, c4, out);
}